// Round 1
// baseline (372.989 us; speedup 1.0000x reference)
//
#include <hip/hip_runtime.h>

typedef unsigned short u16;
typedef __attribute__((ext_vector_type(8))) __bf16 bf16x8;
typedef __attribute__((ext_vector_type(4))) float f32x4;

#define S_LEN 4096
#define D_MODEL 1024
#define NH 16
#define DHEAD 64

__device__ __forceinline__ u16 f2bf(float f){
  unsigned u = __float_as_uint(f);
  u += 0x7FFFu + ((u >> 16) & 1u);   // round-to-nearest-even
  return (u16)(u >> 16);
}

// ---------------- fp32 -> bf16 elementwise ----------------
__global__ __launch_bounds__(256) void cvt_bf16_kernel(const float* __restrict__ in,
                                                       u16* __restrict__ out, int n4){
  int stride = gridDim.x * 256;
  for (int i = blockIdx.x*256 + threadIdx.x; i < n4; i += stride){
    float4 v = reinterpret_cast<const float4*>(in)[i];
    ushort4 o;
    o.x = f2bf(v.x); o.y = f2bf(v.y); o.z = f2bf(v.z); o.w = f2bf(v.w);
    reinterpret_cast<ushort4*>(out)[i] = o;
  }
}

// ------- transpose+convert: in fp32 [nh][R][C] -> out bf16 [nh][C][R] -------
__global__ __launch_bounds__(256) void transpose_cvt_f32_kernel(const float* __restrict__ in,
                                                                u16* __restrict__ out,
                                                                int R, int C){
  __shared__ float tile[64][67];
  int r0 = blockIdx.x*64, c0 = blockIdx.y*64;
  const float* inh = in + (size_t)blockIdx.z * R * C;
  u16* outh = out + (size_t)blockIdx.z * R * C;
  int tid = threadIdx.x;
  #pragma unroll
  for (int c=0;c<4;c++){
    int cl = c*256 + tid;
    int row = cl >> 4, cc = (cl & 15) * 4;
    float4 v = *reinterpret_cast<const float4*>(inh + (size_t)(r0+row)*C + c0 + cc);
    tile[row][cc+0]=v.x; tile[row][cc+1]=v.y; tile[row][cc+2]=v.z; tile[row][cc+3]=v.w;
  }
  __syncthreads();
  #pragma unroll
  for (int c=0;c<4;c++){
    int cl = c*256 + tid;
    int crow = cl >> 4, rc = (cl & 15) * 4;
    ushort4 o;
    o.x = f2bf(tile[rc+0][crow]);
    o.y = f2bf(tile[rc+1][crow]);
    o.z = f2bf(tile[rc+2][crow]);
    o.w = f2bf(tile[rc+3][crow]);
    *reinterpret_cast<ushort4*>(outh + (size_t)(c0+crow)*R + r0 + rc) = o;
  }
}

// ------- transpose bf16: in [nh][R][C] -> out [nh][C][R] -------
__global__ __launch_bounds__(256) void transpose_bf16_kernel(const u16* __restrict__ in,
                                                             u16* __restrict__ out,
                                                             int R, int C){
  __shared__ u16 tile[64][72];   // 144B rows: 16B-aligned, bank-spread
  int r0 = blockIdx.x*64, c0 = blockIdx.y*64;
  const u16* inh = in + (size_t)blockIdx.z * R * C;
  u16* outh = out + (size_t)blockIdx.z * R * C;
  int tid = threadIdx.x;
  #pragma unroll
  for (int c=0;c<2;c++){
    int cl = c*256 + tid;
    int row = cl >> 3, cc = (cl & 7) * 8;
    int4 v = *reinterpret_cast<const int4*>(inh + (size_t)(r0+row)*C + c0 + cc);
    *reinterpret_cast<int4*>(&tile[row][cc]) = v;
  }
  __syncthreads();
  #pragma unroll
  for (int c=0;c<2;c++){
    int cl = c*256 + tid;
    int crow = cl >> 3, rc = (cl & 7) * 8;
    u16 o[8];
    #pragma unroll
    for (int i=0;i<8;i++) o[i] = tile[rc+i][crow];
    *reinterpret_cast<int4*>(outh + (size_t)(c0+crow)*R + r0 + rc) = *reinterpret_cast<int4*>(o);
  }
}

// ------- GEMM: C[M][N] = A[M][K](bf16) @ Bt[N][K]^T(bf16) + bias[N] -------
// MODE 0: write bf16 to [H][M][64] head-major (n -> h=n>>6, kk=n&63)
// MODE 1: write fp32 to [M][N]
template<int MODE>
__global__ __launch_bounds__(256) void gemm_bt_kernel(const u16* __restrict__ A,
                                                      const u16* __restrict__ Bt,
                                                      const float* __restrict__ bias,
                                                      void* __restrict__ dst,
                                                      int M, int N, int K){
  __shared__ unsigned char lsA[128*64*2];
  __shared__ unsigned char lsB[128*64*2];
  int tid = threadIdx.x;
  int bm = blockIdx.y * 128, bn = blockIdx.x * 128;
  int wave = tid >> 6, lane = tid & 63;
  int wm = (wave >> 1) * 64, wn = (wave & 1) * 64;
  int lrow = lane & 15, lgrp = lane >> 4;

  f32x4 acc[4][4] = {};

  for (int k0 = 0; k0 < K; k0 += 64){
    #pragma unroll
    for (int c=0;c<4;c++){
      int cl = c*256 + tid;
      int row = cl >> 3, kc = cl & 7;
      int off = (row*128 + kc*16) ^ ((row & 7) << 4);   // T2 swizzle
      *reinterpret_cast<int4*>(lsA + off) =
        *reinterpret_cast<const int4*>(A + (size_t)(bm+row)*K + k0 + kc*8);
      *reinterpret_cast<int4*>(lsB + off) =
        *reinterpret_cast<const int4*>(Bt + (size_t)(bn+row)*K + k0 + kc*8);
    }
    __syncthreads();
    #pragma unroll
    for (int ks=0;ks<2;ks++){
      bf16x8 af[4], bfr[4];
      #pragma unroll
      for (int i=0;i<4;i++){
        int ar = wm + i*16 + lrow;
        af[i]  = *reinterpret_cast<const bf16x8*>(lsA + ((ar*128 + ks*64 + lgrp*16) ^ ((ar&7)<<4)));
        int br = wn + i*16 + lrow;
        bfr[i] = *reinterpret_cast<const bf16x8*>(lsB + ((br*128 + ks*64 + lgrp*16) ^ ((br&7)<<4)));
      }
      #pragma unroll
      for (int i=0;i<4;i++)
        #pragma unroll
        for (int j=0;j<4;j++)
          acc[i][j] = __builtin_amdgcn_mfma_f32_16x16x32_bf16(af[i], bfr[j], acc[i][j], 0,0,0);
    }
    __syncthreads();
  }

  #pragma unroll
  for (int j=0;j<4;j++){
    int n = bn + wn + j*16 + lrow;
    float bv = bias[n];
    #pragma unroll
    for (int i=0;i<4;i++){
      #pragma unroll
      for (int r=0;r<4;r++){
        int m = bm + wm + i*16 + lgrp*4 + r;
        float val = acc[i][j][r] + bv;
        if (MODE == 0){
          u16* o = (u16*)dst;
          int hh = n >> 6, kk = n & 63;
          o[((size_t)hh*M + m)*64 + kk] = f2bf(val);
        } else {
          float* o = (float*)dst;
          o[(size_t)m*N + n] = val;
        }
      }
    }
  }
}

// ------- causal flash attention, one head x 128 Q-rows per block -------
// qb,kb: [H][S][64] bf16 ; vtb: [H][64][S] bf16 ; catb: [S][1024] bf16
__global__ __launch_bounds__(256) void flash_attn_kernel(const u16* __restrict__ qb,
                                                         const u16* __restrict__ kb,
                                                         const u16* __restrict__ vtb,
                                                         u16* __restrict__ catb){
  int h = blockIdx.y;
  int q0 = blockIdx.x * 128;
  int tid = threadIdx.x, wave = tid >> 6, lane = tid & 63;
  int lrow = lane & 15, lgrp = lane >> 4;
  const u16* qh  = qb  + (size_t)h * S_LEN * 64;
  const u16* kh  = kb  + (size_t)h * S_LEN * 64;
  const u16* vth = vtb + (size_t)h * 64 * S_LEN;

  __shared__ unsigned char lsK[64*64*2];
  __shared__ unsigned char lsV[64*64*2];
  __shared__ unsigned char lsP[4][32*72*2];   // per-wave P relayout buffer

  // hoist Q fragments (rows q0 + wave*32 .. +31)
  bf16x8 qf[2][2];
  #pragma unroll
  for (int rf=0;rf<2;rf++)
    #pragma unroll
    for (int ks=0;ks<2;ks++)
      qf[rf][ks] = *reinterpret_cast<const bf16x8*>(
          qh + (size_t)(q0 + wave*32 + rf*16 + lrow)*64 + ks*32 + lgrp*8);

  f32x4 o_acc[2][4] = {};
  float m_run[2][4], l_run[2][4];
  #pragma unroll
  for (int rf=0;rf<2;rf++)
    #pragma unroll
    for (int r=0;r<4;r++){ m_run[rf][r] = -1e30f; l_run[rf][r] = 0.f; }

  int nt = 2*blockIdx.x + 2;   // KV tiles covering kv <= q0+127
  for (int t=0;t<nt;t++){
    int kv0 = t*64;
    #pragma unroll
    for (int c=0;c<2;c++){
      int cl = c*256 + tid;
      int row = cl >> 3, kc = cl & 7;
      int off = (row*128 + kc*16) ^ ((row&7)<<4);
      *reinterpret_cast<int4*>(lsK + off) =
        *reinterpret_cast<const int4*>(kh + (size_t)(kv0+row)*64 + kc*8);
      *reinterpret_cast<int4*>(lsV + off) =
        *reinterpret_cast<const int4*>(vth + (size_t)row*S_LEN + kv0 + kc*8);
    }
    __syncthreads();

    // QK^T : A=Q rows, B[k=d][col=kv] read from lsK[kv][d]
    bf16x8 kf[4][2];
    #pragma unroll
    for (int cf=0;cf<4;cf++)
      #pragma unroll
      for (int ks=0;ks<2;ks++){
        int row = cf*16 + lrow;
        kf[cf][ks] = *reinterpret_cast<const bf16x8*>(
            lsK + ((row*128 + ks*64 + lgrp*16) ^ ((row&7)<<4)));
      }
    f32x4 s_acc[2][4] = {};
    #pragma unroll
    for (int rf=0;rf<2;rf++)
      #pragma unroll
      for (int cf=0;cf<4;cf++)
        #pragma unroll
        for (int ks=0;ks<2;ks++)
          s_acc[rf][cf] = __builtin_amdgcn_mfma_f32_16x16x32_bf16(qf[rf][ks], kf[cf][ks], s_acc[rf][cf], 0,0,0);

    // online softmax (16-lane shfl reductions), write P bf16 to per-wave LDS
    #pragma unroll
    for (int rf=0;rf<2;rf++){
      #pragma unroll
      for (int r=0;r<4;r++){
        int grow = q0 + wave*32 + rf*16 + lgrp*4 + r;
        float sv[4]; float mx = -1e30f;
        #pragma unroll
        for (int cf=0;cf<4;cf++){
          float v = s_acc[rf][cf][r] * 0.125f;
          int gcol = kv0 + cf*16 + lrow;
          if (gcol > grow) v = -1e30f;     // causal (double-mask == same result)
          sv[cf] = v; mx = fmaxf(mx, v);
        }
        #pragma unroll
        for (int d=1; d<16; d<<=1) mx = fmaxf(mx, __shfl_xor(mx, d));
        float mnew = fmaxf(m_run[rf][r], mx);
        float alpha = __expf(m_run[rf][r] - mnew);
        float ps = 0.f;
        int prow = rf*16 + lgrp*4 + r;
        #pragma unroll
        for (int cf=0;cf<4;cf++){
          float p = (sv[cf] < -1e29f) ? 0.f : __expf(sv[cf] - mnew);  // guard all-masked rows
          ps += p;
          *reinterpret_cast<u16*>(&lsP[wave][(prow*72 + cf*16 + lrow)*2]) = f2bf(p);
        }
        #pragma unroll
        for (int d=1; d<16; d<<=1) ps += __shfl_xor(ps, d);
        l_run[rf][r] = l_run[rf][r]*alpha + ps;
        m_run[rf][r] = mnew;
        #pragma unroll
        for (int cf=0;cf<4;cf++) o_acc[rf][cf][r] *= alpha;
      }
    }

    // PV : A=P (from lsP, A-frag layout), B[k=kv][col=vd] from lsV[vd][kv]
    bf16x8 vf[4][2];
    #pragma unroll
    for (int cf=0;cf<4;cf++)
      #pragma unroll
      for (int ks=0;ks<2;ks++){
        int row = cf*16 + lrow;
        vf[cf][ks] = *reinterpret_cast<const bf16x8*>(
            lsV + ((row*128 + ks*64 + lgrp*16) ^ ((row&7)<<4)));
      }
    #pragma unroll
    for (int rf=0;rf<2;rf++){
      #pragma unroll
      for (int ks=0;ks<2;ks++){
        bf16x8 pa = *reinterpret_cast<const bf16x8*>(
            &lsP[wave][((rf*16 + lrow)*72 + ks*32 + lgrp*8)*2]);
        #pragma unroll
        for (int cf=0;cf<4;cf++)
          o_acc[rf][cf] = __builtin_amdgcn_mfma_f32_16x16x32_bf16(pa, vf[cf][ks], o_acc[rf][cf], 0,0,0);
      }
    }
    __syncthreads();
  }

  #pragma unroll
  for (int rf=0;rf<2;rf++)
    #pragma unroll
    for (int r=0;r<4;r++){
      float inv = 1.f / l_run[rf][r];
      int grow = q0 + wave*32 + rf*16 + lgrp*4 + r;
      #pragma unroll
      for (int cf=0;cf<4;cf++)
        catb[(size_t)grow*D_MODEL + h*64 + cf*16 + lrow] = f2bf(o_acc[rf][cf][r] * inv);
    }
}

extern "C" void kernel_launch(void* const* d_in, const int* in_sizes, int n_in,
                              void* d_out, int out_size, void* d_ws, size_t ws_size,
                              hipStream_t stream){
  (void)in_sizes; (void)n_in; (void)out_size; (void)ws_size;
  const float* V  = (const float*)d_in[0];
  const float* Km = (const float*)d_in[1];
  const float* Q  = (const float*)d_in[2];
  const float* WQ = (const float*)d_in[3];
  const float* bQ = (const float*)d_in[4];
  const float* WK = (const float*)d_in[5];
  const float* bK = (const float*)d_in[6];
  const float* WV = (const float*)d_in[7];
  const float* bV = (const float*)d_in[8];
  const float* WO = (const float*)d_in[9];
  const float* bO = (const float*)d_in[10];
  float* out = (float*)d_out;

  char* ws = (char*)d_ws;
  const size_t SZ_SD = (size_t)S_LEN * D_MODEL * 2;    // 8 MiB per [S][D] bf16
  const size_t SZ_W  = (size_t)D_MODEL * D_MODEL * 2;  // 2 MiB per [1024][1024] bf16
  u16* Qb   = (u16*)(ws);
  u16* Kb   = (u16*)(ws + SZ_SD);
  u16* Vb   = (u16*)(ws + 2*SZ_SD);
  u16* WtQ  = (u16*)(ws + 3*SZ_SD);
  u16* WtK  = (u16*)(ws + 3*SZ_SD + SZ_W);
  u16* WtV  = (u16*)(ws + 3*SZ_SD + 2*SZ_W);
  u16* WtO  = (u16*)(ws + 3*SZ_SD + 3*SZ_W);
  u16* qbuf = (u16*)(ws + 3*SZ_SD + 4*SZ_W);
  u16* kbuf = (u16*)(ws + 4*SZ_SD + 4*SZ_W);
  u16* vbuf = (u16*)(ws + 5*SZ_SD + 4*SZ_W);
  u16* vtb  = (u16*)(ws + 6*SZ_SD + 4*SZ_W);
  u16* catb = (u16*)(ws + 7*SZ_SD + 4*SZ_W);
  // total workspace use: 8*SZ_SD + 4*SZ_W = 72 MiB

  int n4 = S_LEN*D_MODEL/4;
  cvt_bf16_kernel<<<4096,256,0,stream>>>(Q,  Qb, n4);
  cvt_bf16_kernel<<<4096,256,0,stream>>>(Km, Kb, n4);
  cvt_bf16_kernel<<<4096,256,0,stream>>>(V,  Vb, n4);
  transpose_cvt_f32_kernel<<<dim3(16,1,16),256,0,stream>>>(WQ, WtQ, 1024, 64);
  transpose_cvt_f32_kernel<<<dim3(16,1,16),256,0,stream>>>(WK, WtK, 1024, 64);
  transpose_cvt_f32_kernel<<<dim3(16,1,16),256,0,stream>>>(WV, WtV, 1024, 64);
  transpose_cvt_f32_kernel<<<dim3(16,16,1),256,0,stream>>>(WO, WtO, 1024, 1024);
  gemm_bt_kernel<0><<<dim3(8,32),256,0,stream>>>(Qb, WtQ, bQ, qbuf, S_LEN, D_MODEL, D_MODEL);
  gemm_bt_kernel<0><<<dim3(8,32),256,0,stream>>>(Kb, WtK, bK, kbuf, S_LEN, D_MODEL, D_MODEL);
  gemm_bt_kernel<0><<<dim3(8,32),256,0,stream>>>(Vb, WtV, bV, vbuf, S_LEN, D_MODEL, D_MODEL);
  transpose_bf16_kernel<<<dim3(64,1,16),256,0,stream>>>(vbuf, vtb, S_LEN, 64);
  flash_attn_kernel<<<dim3(32,16),256,0,stream>>>(qbuf, kbuf, vtb, catb);
  gemm_bt_kernel<1><<<dim3(8,32),256,0,stream>>>(catb, WtO, bO, out, S_LEN, D_MODEL, D_MODEL);
}

// Round 2
// 238.889 us; speedup vs baseline: 1.5613x; 1.5613x over previous
//
#include <hip/hip_runtime.h>

typedef unsigned short u16;
typedef __attribute__((ext_vector_type(8))) __bf16 bf16x8;
typedef __attribute__((ext_vector_type(4))) float f32x4;

#define S_LEN 4096
#define D_MODEL 1024
#define NH 16
#define DHEAD 64

__device__ __forceinline__ u16 f2bf(float f){
  unsigned u = __float_as_uint(f);
  u += 0x7FFFu + ((u >> 16) & 1u);   // round-to-nearest-even
  return (u16)(u >> 16);
}

__device__ __forceinline__ void gload_lds16(const void* g, void* l){
  __builtin_amdgcn_global_load_lds((const __attribute__((address_space(1))) void*)g,
                                   (__attribute__((address_space(3))) void*)l, 16, 0, 0);
}

// ---------------- fp32 -> bf16 elementwise ----------------
__global__ __launch_bounds__(256) void cvt_bf16_kernel(const float* __restrict__ in,
                                                       u16* __restrict__ out, int n4){
  int stride = gridDim.x * 256;
  for (int i = blockIdx.x*256 + threadIdx.x; i < n4; i += stride){
    float4 v = reinterpret_cast<const float4*>(in)[i];
    ushort4 o;
    o.x = f2bf(v.x); o.y = f2bf(v.y); o.z = f2bf(v.z); o.w = f2bf(v.w);
    reinterpret_cast<ushort4*>(out)[i] = o;
  }
}

// ------- transpose+convert: in fp32 [nh][R][C] -> out bf16 [nh][C][R] -------
__global__ __launch_bounds__(256) void transpose_cvt_f32_kernel(const float* __restrict__ in,
                                                                u16* __restrict__ out,
                                                                int R, int C){
  __shared__ float tile[64][67];
  int r0 = blockIdx.x*64, c0 = blockIdx.y*64;
  const float* inh = in + (size_t)blockIdx.z * R * C;
  u16* outh = out + (size_t)blockIdx.z * R * C;
  int tid = threadIdx.x;
  #pragma unroll
  for (int c=0;c<4;c++){
    int cl = c*256 + tid;
    int row = cl >> 4, cc = (cl & 15) * 4;
    float4 v = *reinterpret_cast<const float4*>(inh + (size_t)(r0+row)*C + c0 + cc);
    tile[row][cc+0]=v.x; tile[row][cc+1]=v.y; tile[row][cc+2]=v.z; tile[row][cc+3]=v.w;
  }
  __syncthreads();
  #pragma unroll
  for (int c=0;c<4;c++){
    int cl = c*256 + tid;
    int crow = cl >> 4, rc = (cl & 15) * 4;
    ushort4 o;
    o.x = f2bf(tile[rc+0][crow]);
    o.y = f2bf(tile[rc+1][crow]);
    o.z = f2bf(tile[rc+2][crow]);
    o.w = f2bf(tile[rc+3][crow]);
    *reinterpret_cast<ushort4*>(outh + (size_t)(c0+crow)*R + r0 + rc) = o;
  }
}

// ------- transpose bf16: in [nh][R][C] -> out [nh][C][R] -------
__global__ __launch_bounds__(256) void transpose_bf16_kernel(const u16* __restrict__ in,
                                                             u16* __restrict__ out,
                                                             int R, int C){
  __shared__ u16 tile[64][72];
  int r0 = blockIdx.x*64, c0 = blockIdx.y*64;
  const u16* inh = in + (size_t)blockIdx.z * R * C;
  u16* outh = out + (size_t)blockIdx.z * R * C;
  int tid = threadIdx.x;
  #pragma unroll
  for (int c=0;c<2;c++){
    int cl = c*256 + tid;
    int row = cl >> 3, cc = (cl & 7) * 8;
    int4 v = *reinterpret_cast<const int4*>(inh + (size_t)(r0+row)*C + c0 + cc);
    *reinterpret_cast<int4*>(&tile[row][cc]) = v;
  }
  __syncthreads();
  #pragma unroll
  for (int c=0;c<2;c++){
    int cl = c*256 + tid;
    int crow = cl >> 3, rc = (cl & 7) * 8;
    u16 o[8];
    #pragma unroll
    for (int i=0;i<8;i++) o[i] = tile[rc+i][crow];
    *reinterpret_cast<int4*>(outh + (size_t)(c0+crow)*R + r0 + rc) = *reinterpret_cast<int4*>(o);
  }
}

// ------- GEMM: C[M][N] = A[M][K](bf16) @ Bt[N][K]^T(bf16) + bias[N], *oscale -------
// MODE 0: write bf16 to [H][M][64] head-major; MODE 1: write fp32 to [M][N]
// global_load_lds double-buffered staging, pre-swizzled source (rule #21)
template<int MODE>
__global__ __launch_bounds__(256) void gemm_bt_kernel(const u16* __restrict__ A,
                                                      const u16* __restrict__ Bt,
                                                      const float* __restrict__ bias,
                                                      void* __restrict__ dst,
                                                      int M, int N, int K, float oscale){
  __shared__ unsigned char lsA[2][128*64*2];
  __shared__ unsigned char lsB[2][128*64*2];
  int tid = threadIdx.x;
  int bm = blockIdx.y * 128, bn = blockIdx.x * 128;
  int wave = tid >> 6, lane = tid & 63;
  int wm = (wave >> 1) * 64, wn = (wave & 1) * 64;
  int lrow = lane & 15, lgrp = lane >> 4;

  f32x4 acc[4][4] = {};

  auto STAGE = [&](int buf, int k0){
    #pragma unroll
    for (int c=0;c<8;c++){
      int chunk = c*4 + wave;            // 0..31, wave-uniform
      int ch = chunk & 15;
      int u = ch*64 + lane;              // 16B unit index
      int row = u >> 3, kc = u & 7;
      const u16* src = (chunk < 16 ? A + (size_t)(bm+row)*K : Bt + (size_t)(bn+row)*K)
                       + k0 + ((kc ^ (row & 7)) << 3);
      unsigned char* d = (chunk < 16 ? lsA[buf] : lsB[buf]) + ch*1024;
      gload_lds16(src, d);
    }
  };

  STAGE(0, 0);
  int cur = 0;
  for (int k0 = 0; k0 < K; k0 += 64){
    __syncthreads();                     // drains prefetch (vmcnt0) + protects buf reuse
    if (k0 + 64 < K) STAGE(cur^1, k0 + 64);
    #pragma unroll
    for (int ks=0;ks<2;ks++){
      bf16x8 af[4], bfr[4];
      #pragma unroll
      for (int i=0;i<4;i++){
        int ar = wm + i*16 + lrow;
        af[i]  = *reinterpret_cast<const bf16x8*>(lsA[cur] + ((ar*128 + ks*64 + lgrp*16) ^ ((ar&7)<<4)));
        int br = wn + i*16 + lrow;
        bfr[i] = *reinterpret_cast<const bf16x8*>(lsB[cur] + ((br*128 + ks*64 + lgrp*16) ^ ((br&7)<<4)));
      }
      #pragma unroll
      for (int i=0;i<4;i++)
        #pragma unroll
        for (int j=0;j<4;j++)
          acc[i][j] = __builtin_amdgcn_mfma_f32_16x16x32_bf16(af[i], bfr[j], acc[i][j], 0,0,0);
    }
    cur ^= 1;
  }

  #pragma unroll
  for (int j=0;j<4;j++){
    int n = bn + wn + j*16 + lrow;
    float bv = bias[n];
    #pragma unroll
    for (int i=0;i<4;i++){
      #pragma unroll
      for (int r=0;r<4;r++){
        int m = bm + wm + i*16 + lgrp*4 + r;
        float val = (acc[i][j][r] + bv) * oscale;
        if (MODE == 0){
          u16* o = (u16*)dst;
          int hh = n >> 6, kk = n & 63;
          o[((size_t)hh*M + m)*64 + kk] = f2bf(val);
        } else {
          float* o = (float*)dst;
          o[(size_t)m*N + n] = val;
        }
      }
    }
  }
}

// ------- causal flash attention, paired Q-tiles for load balance -------
// qb (PRE-SCALED by 0.125*log2e), kb: [H][S][64] bf16 ; vtb: [H][64][S] bf16 ; catb: [S][1024] bf16
// block = 4 waves x 16 Q-rows = 64-row Q-tile; block pi handles Q-tiles (63-pi) then (pi)
__global__ __launch_bounds__(256) void flash_attn_kernel(const u16* __restrict__ qb,
                                                         const u16* __restrict__ kb,
                                                         const u16* __restrict__ vtb,
                                                         u16* __restrict__ catb){
  int h = blockIdx.y;
  int pi = blockIdx.x;                  // 0..31
  int qtA = 63 - pi, qtB = pi;
  int ntA = qtA + 1, ntB = qtB + 1;
  int ntT = ntA + ntB;                  // 65 for every block
  int tid = threadIdx.x, wave = tid >> 6, lane = tid & 63;
  int lrow = lane & 15, lgrp = lane >> 4;
  const u16* qh  = qb  + (size_t)h * S_LEN * 64;
  const u16* kh  = kb  + (size_t)h * S_LEN * 64;
  const u16* vth = vtb + (size_t)h * 64 * S_LEN;

  __shared__ unsigned char lsK[2][64*64*2];
  __shared__ unsigned char lsV[2][64*64*2];
  __shared__ __bf16 lsP[4][16*72];      // per-wave P relayout (stride 72 elems = 144B)

  // hoist Q fragments for both halves
  bf16x8 qfA[2], qfB[2];
  #pragma unroll
  for (int ks=0;ks<2;ks++){
    qfA[ks] = *reinterpret_cast<const bf16x8*>(qh + (size_t)(qtA*64 + wave*16 + lrow)*64 + ks*32 + lgrp*8);
    qfB[ks] = *reinterpret_cast<const bf16x8*>(qh + (size_t)(qtB*64 + wave*16 + lrow)*64 + ks*32 + lgrp*8);
  }
  bf16x8 onesv;
  #pragma unroll
  for (int i=0;i<8;i++) onesv[i] = (__bf16)1.0f;

  f32x4 o_acc[4] = {};
  f32x4 l_acc = {};
  float m_run[4];
  #pragma unroll
  for (int r=0;r<4;r++) m_run[r] = -1e30f;

  auto STAGE = [&](int buf, int jj){
    int kv0 = (jj < ntA ? jj : jj - ntA) * 64;
    #pragma unroll
    for (int c=0;c<4;c++){
      int chunk = c*4 + wave;           // 0..15, wave-uniform; 0-7 = K, 8-15 = V
      int ch = chunk & 7;
      int u = ch*64 + lane;
      int row = u >> 3, kc = u & 7;
      const u16* src;
      unsigned char* d;
      if (chunk < 8){
        src = kh + (size_t)(kv0+row)*64 + ((kc ^ (row&7)) << 3);
        d = lsK[buf] + ch*1024;
      } else {
        src = vth + (size_t)row*S_LEN + kv0 + ((kc ^ (row&7)) << 3);
        d = lsV[buf] + ch*1024;
      }
      gload_lds16(src, d);
    }
  };

  STAGE(0, 0);
  int cur = 0;
  for (int j = 0; j < ntT; j++){
    __syncthreads();                    // buf[cur] ready; safe to overwrite buf[cur^1]
    if (j + 1 < ntT) STAGE(cur^1, j + 1);

    bool isA = j < ntA;
    int qt = isA ? qtA : qtB;
    int tj = isA ? j : j - ntA;
    bool diag = (tj == qt);
    bf16x8 q0f = isA ? qfA[0] : qfB[0];
    bf16x8 q1f = isA ? qfA[1] : qfB[1];

    // ---- QK^T ----
    bf16x8 kf[4][2];
    #pragma unroll
    for (int cf=0;cf<4;cf++)
      #pragma unroll
      for (int ks=0;ks<2;ks++){
        int row = cf*16 + lrow;
        kf[cf][ks] = *reinterpret_cast<const bf16x8*>(
            lsK[cur] + ((row*128 + ks*64 + lgrp*16) ^ ((row&7)<<4)));
      }
    f32x4 s_acc[4] = {};
    __builtin_amdgcn_s_setprio(1);
    #pragma unroll
    for (int cf=0;cf<4;cf++){
      s_acc[cf] = __builtin_amdgcn_mfma_f32_16x16x32_bf16(q0f, kf[cf][0], s_acc[cf], 0,0,0);
      s_acc[cf] = __builtin_amdgcn_mfma_f32_16x16x32_bf16(q1f, kf[cf][1], s_acc[cf], 0,0,0);
    }
    __builtin_amdgcn_s_setprio(0);

    // ---- online softmax (exp2 domain; Q pre-scaled) ----
    if (diag){
      int rid = wave*16 + lgrp*4;
      #pragma unroll
      for (int cf=0;cf<4;cf++)
        #pragma unroll
        for (int r=0;r<4;r++)
          if (cf*16 + lrow > rid + r) s_acc[cf][r] = -1e30f;
    }
    float mxr[4];
    #pragma unroll
    for (int r=0;r<4;r++){
      float m0 = fmaxf(fmaxf(s_acc[0][r], s_acc[1][r]), fmaxf(s_acc[2][r], s_acc[3][r]));
      #pragma unroll
      for (int d=1; d<16; d<<=1) m0 = fmaxf(m0, __shfl_xor(m0, d));
      mxr[r] = m0;
    }
    bool nr = true;
    #pragma unroll
    for (int r=0;r<4;r++) nr = nr && (mxr[r] <= m_run[r] + 11.54f);
    if (!__all(nr)){                    // defer-max: skip rescale when max barely grew
      #pragma unroll
      for (int r=0;r<4;r++){
        float mnew = fmaxf(m_run[r], mxr[r]);
        float al = __builtin_amdgcn_exp2f(m_run[r] - mnew);
        m_run[r] = mnew;
        l_acc[r] *= al;
        #pragma unroll
        for (int cf=0;cf<4;cf++) o_acc[cf][r] *= al;
      }
    }
    #pragma unroll
    for (int r=0;r<4;r++){
      int prow = lgrp*4 + r;
      #pragma unroll
      for (int cf=0;cf<4;cf++){
        float p = __builtin_amdgcn_exp2f(s_acc[cf][r] - m_run[r]);
        lsP[wave][prow*72 + cf*16 + lrow] = (__bf16)p;
      }
    }

    // ---- PV (+ ones column accumulates l) ----
    bf16x8 vf[4][2];
    #pragma unroll
    for (int cf=0;cf<4;cf++)
      #pragma unroll
      for (int ks=0;ks<2;ks++){
        int row = cf*16 + lrow;
        vf[cf][ks] = *reinterpret_cast<const bf16x8*>(
            lsV[cur] + ((row*128 + ks*64 + lgrp*16) ^ ((row&7)<<4)));
      }
    bf16x8 pa[2];
    #pragma unroll
    for (int ks=0;ks<2;ks++)
      pa[ks] = *reinterpret_cast<const bf16x8*>(&lsP[wave][lrow*72 + ks*32 + lgrp*8]);
    __builtin_amdgcn_s_setprio(1);
    #pragma unroll
    for (int ks=0;ks<2;ks++){
      #pragma unroll
      for (int cf=0;cf<4;cf++)
        o_acc[cf] = __builtin_amdgcn_mfma_f32_16x16x32_bf16(pa[ks], vf[cf][ks], o_acc[cf], 0,0,0);
      l_acc = __builtin_amdgcn_mfma_f32_16x16x32_bf16(pa[ks], onesv, l_acc, 0,0,0);
    }
    __builtin_amdgcn_s_setprio(0);

    // ---- epilogue at half boundaries ----
    if (j == ntA - 1 || j == ntT - 1){
      int q0e = (j == ntA - 1) ? qtA*64 : qtB*64;
      #pragma unroll
      for (int r=0;r<4;r++){
        float inv = 1.0f / l_acc[r];
        int grow = q0e + wave*16 + lgrp*4 + r;
        #pragma unroll
        for (int cf=0;cf<4;cf++)
          catb[(size_t)grow*D_MODEL + h*64 + cf*16 + lrow] = f2bf(o_acc[cf][r] * inv);
      }
      if (j == ntA - 1){
        #pragma unroll
        for (int cf=0;cf<4;cf++) o_acc[cf] = f32x4{0.f,0.f,0.f,0.f};
        l_acc = f32x4{0.f,0.f,0.f,0.f};
        #pragma unroll
        for (int r=0;r<4;r++) m_run[r] = -1e30f;
      }
    }
    cur ^= 1;
  }
}

extern "C" void kernel_launch(void* const* d_in, const int* in_sizes, int n_in,
                              void* d_out, int out_size, void* d_ws, size_t ws_size,
                              hipStream_t stream){
  (void)in_sizes; (void)n_in; (void)out_size; (void)ws_size;
  const float* V  = (const float*)d_in[0];
  const float* Km = (const float*)d_in[1];
  const float* Q  = (const float*)d_in[2];
  const float* WQ = (const float*)d_in[3];
  const float* bQ = (const float*)d_in[4];
  const float* WK = (const float*)d_in[5];
  const float* bK = (const float*)d_in[6];
  const float* WV = (const float*)d_in[7];
  const float* bV = (const float*)d_in[8];
  const float* WO = (const float*)d_in[9];
  const float* bO = (const float*)d_in[10];
  float* out = (float*)d_out;

  char* ws = (char*)d_ws;
  const size_t SZ_SD = (size_t)S_LEN * D_MODEL * 2;
  const size_t SZ_W  = (size_t)D_MODEL * D_MODEL * 2;
  u16* Qb   = (u16*)(ws);
  u16* Kb   = (u16*)(ws + SZ_SD);
  u16* Vb   = (u16*)(ws + 2*SZ_SD);
  u16* WtQ  = (u16*)(ws + 3*SZ_SD);
  u16* WtK  = (u16*)(ws + 3*SZ_SD + SZ_W);
  u16* WtV  = (u16*)(ws + 3*SZ_SD + 2*SZ_W);
  u16* WtO  = (u16*)(ws + 3*SZ_SD + 3*SZ_W);
  u16* qbuf = (u16*)(ws + 3*SZ_SD + 4*SZ_W);
  u16* kbuf = (u16*)(ws + 4*SZ_SD + 4*SZ_W);
  u16* vbuf = (u16*)(ws + 5*SZ_SD + 4*SZ_W);
  u16* vtb  = (u16*)(ws + 6*SZ_SD + 4*SZ_W);
  u16* catb = (u16*)(ws + 7*SZ_SD + 4*SZ_W);

  const float QSCALE = 0.18033688011112042f;   // 0.125 * log2(e): exp2-domain softmax

  int n4 = S_LEN*D_MODEL/4;
  cvt_bf16_kernel<<<4096,256,0,stream>>>(Q,  Qb, n4);
  cvt_bf16_kernel<<<4096,256,0,stream>>>(Km, Kb, n4);
  cvt_bf16_kernel<<<4096,256,0,stream>>>(V,  Vb, n4);
  transpose_cvt_f32_kernel<<<dim3(16,1,16),256,0,stream>>>(WQ, WtQ, 1024, 64);
  transpose_cvt_f32_kernel<<<dim3(16,1,16),256,0,stream>>>(WK, WtK, 1024, 64);
  transpose_cvt_f32_kernel<<<dim3(16,1,16),256,0,stream>>>(WV, WtV, 1024, 64);
  transpose_cvt_f32_kernel<<<dim3(16,16,1),256,0,stream>>>(WO, WtO, 1024, 1024);
  gemm_bt_kernel<0><<<dim3(8,32),256,0,stream>>>(Qb, WtQ, bQ, qbuf, S_LEN, D_MODEL, D_MODEL, QSCALE);
  gemm_bt_kernel<0><<<dim3(8,32),256,0,stream>>>(Kb, WtK, bK, kbuf, S_LEN, D_MODEL, D_MODEL, 1.0f);
  gemm_bt_kernel<0><<<dim3(8,32),256,0,stream>>>(Vb, WtV, bV, vbuf, S_LEN, D_MODEL, D_MODEL, 1.0f);
  transpose_bf16_kernel<<<dim3(64,1,16),256,0,stream>>>(vbuf, vtb, S_LEN, 64);
  flash_attn_kernel<<<dim3(32,16),256,0,stream>>>(qbuf, kbuf, vtb, catb);
  gemm_bt_kernel<1><<<dim3(8,32),256,0,stream>>>(catb, WtO, bO, out, S_LEN, D_MODEL, D_MODEL, 1.0f);
}

// Round 4
// 207.577 us; speedup vs baseline: 1.7969x; 1.1508x over previous
//
#include <hip/hip_runtime.h>

typedef unsigned short u16;
typedef unsigned int u32;
typedef __attribute__((ext_vector_type(8))) __bf16 bf16x8;
typedef __attribute__((ext_vector_type(4))) float f32x4;
typedef __attribute__((ext_vector_type(16))) float f32x16;

#define S_LEN 4096
#define D_MODEL 1024
#define NH 16
#define DHEAD 64

__device__ __forceinline__ u16 f2bf(float f){
  unsigned u = __float_as_uint(f);
  u += 0x7FFFu + ((u >> 16) & 1u);   // RTNE
  return (u16)(u >> 16);
}

__device__ __forceinline__ void gload_lds16(const void* g, void* l){
  __builtin_amdgcn_global_load_lds((const __attribute__((address_space(1))) void*)g,
                                   (__attribute__((address_space(3))) void*)l, 16, 0, 0);
}

// ---------------- fp32 -> bf16, three tensors in one launch ----------------
__global__ __launch_bounds__(256) void cvt3_kernel(const float* __restrict__ q,
                                                   const float* __restrict__ k,
                                                   const float* __restrict__ v,
                                                   u16* __restrict__ oq,
                                                   u16* __restrict__ ok,
                                                   u16* __restrict__ ov){
  int z = blockIdx.y;
  const float* in = (z==0)? q : (z==1)? k : v;
  u16* out = (z==0)? oq : (z==1)? ok : ov;
  int i = blockIdx.x*256 + threadIdx.x;
  float4 w = reinterpret_cast<const float4*>(in)[i];
  ushort4 o;
  o.x = f2bf(w.x); o.y = f2bf(w.y); o.z = f2bf(w.z); o.w = f2bf(w.w);
  reinterpret_cast<ushort4*>(out)[i] = o;
}

// ------- transpose+convert QKV weights: [16][1024][64] fp32 -> [16][64][1024] bf16 -------
__global__ __launch_bounds__(256) void tcvt_qkv_kernel(const float* __restrict__ wq,
                                                       const float* __restrict__ wk,
                                                       const float* __restrict__ wv,
                                                       u16* __restrict__ oq,
                                                       u16* __restrict__ ok,
                                                       u16* __restrict__ ov){
  int which = blockIdx.y;
  const float* in = (which==0)? wq : (which==1)? wk : wv;
  u16* out = (which==0)? oq : (which==1)? ok : ov;
  __shared__ float tile[64][67];
  int z = blockIdx.z;
  const float* inh = in + (size_t)z*1024*64;
  u16* outh = out + (size_t)z*1024*64;
  int tid = threadIdx.x;
  int r0 = blockIdx.x*64;
  #pragma unroll
  for (int c=0;c<4;c++){
    int cl = c*256 + tid;
    int row = cl >> 4, cc = (cl & 15) * 4;
    float4 v = *reinterpret_cast<const float4*>(inh + (size_t)(r0+row)*64 + cc);
    tile[row][cc+0]=v.x; tile[row][cc+1]=v.y; tile[row][cc+2]=v.z; tile[row][cc+3]=v.w;
  }
  __syncthreads();
  #pragma unroll
  for (int c=0;c<4;c++){
    int cl = c*256 + tid;
    int crow = cl >> 4, rc = (cl & 15) * 4;
    ushort4 o;
    o.x = f2bf(tile[rc+0][crow]);
    o.y = f2bf(tile[rc+1][crow]);
    o.z = f2bf(tile[rc+2][crow]);
    o.w = f2bf(tile[rc+3][crow]);
    *reinterpret_cast<ushort4*>(outh + (size_t)crow*1024 + r0 + rc) = o;
  }
}

// ------- transpose+convert WO: [1024][1024] fp32 -> WO^T bf16 -------
__global__ __launch_bounds__(256) void tcvt_wo_kernel(const float* __restrict__ in,
                                                      u16* __restrict__ out){
  __shared__ float tile[64][67];
  int r0 = blockIdx.x*64, c0 = blockIdx.y*64;
  int tid = threadIdx.x;
  #pragma unroll
  for (int c=0;c<4;c++){
    int cl = c*256 + tid;
    int row = cl >> 4, cc = (cl & 15) * 4;
    float4 v = *reinterpret_cast<const float4*>(in + (size_t)(r0+row)*1024 + c0 + cc);
    tile[row][cc+0]=v.x; tile[row][cc+1]=v.y; tile[row][cc+2]=v.z; tile[row][cc+3]=v.w;
  }
  __syncthreads();
  #pragma unroll
  for (int c=0;c<4;c++){
    int cl = c*256 + tid;
    int crow = cl >> 4, rc = (cl & 15) * 4;
    ushort4 o;
    o.x = f2bf(tile[rc+0][crow]);
    o.y = f2bf(tile[rc+1][crow]);
    o.z = f2bf(tile[rc+2][crow]);
    o.w = f2bf(tile[rc+3][crow]);
    *reinterpret_cast<ushort4*>(out + (size_t)(c0+crow)*1024 + r0 + rc) = o;
  }
}

// ------- GEMM: C[M][N] = A[M][K] @ Bt[N][K]^T + bias[N], *oscale ; 8 waves -------
// MODE 0: bf16 -> [H][M][64]; MODE 1: fp32 -> [M][N]; MODE 2: bf16 -> [H][64][M] (V^T)
template<int MODE>
__global__ __launch_bounds__(512) void gemm_bt_kernel(const u16* __restrict__ A,
                                                      const u16* __restrict__ Bt,
                                                      const float* __restrict__ bias,
                                                      void* __restrict__ dst,
                                                      int M, int N, int K, float oscale){
  __shared__ __align__(16) unsigned char lsA[2][16384];
  __shared__ __align__(16) unsigned char lsB[2][16384];
  int tid = threadIdx.x;
  int bm = blockIdx.y * 128, bn = blockIdx.x * 128;
  int wave = tid >> 6, lane = tid & 63;
  int wm = (wave >> 1) * 32, wn = (wave & 1) * 64;
  int lrow = lane & 15, lgrp = lane >> 4;

  f32x4 acc[2][4] = {};

  auto STAGE = [&](int buf, int k0){
    #pragma unroll
    for (int c=0;c<4;c++){
      int id = c*512 + tid;              // 0..2047 ; c<2 -> A, c>=2 -> B (uniform)
      int r = (id & 1023) >> 3;
      int kc = id & 7;
      int cs = (kc ^ (r & 7)) << 3;      // pre-swizzled source column (rule #21)
      if (id < 1024)
        gload_lds16(A + (size_t)(bm+r)*K + k0 + cs, lsA[buf] + ((id & 1023) << 4));
      else
        gload_lds16(Bt + (size_t)(bn+r)*K + k0 + cs, lsB[buf] + ((id & 1023) << 4));
    }
  };

  STAGE(0, 0);
  int cur = 0;
  for (int k0 = 0; k0 < K; k0 += 64){
    __syncthreads();
    if (k0 + 64 < K) STAGE(cur^1, k0 + 64);
    #pragma unroll
    for (int ks=0;ks<2;ks++){
      bf16x8 af[2], bfr[4];
      #pragma unroll
      for (int i=0;i<2;i++){
        int ar = wm + i*16 + lrow;
        af[i] = *reinterpret_cast<const bf16x8*>(lsA[cur] + ((ar*128 + ks*64 + lgrp*16) ^ ((ar&7)<<4)));
      }
      #pragma unroll
      for (int j=0;j<4;j++){
        int br = wn + j*16 + lrow;
        bfr[j] = *reinterpret_cast<const bf16x8*>(lsB[cur] + ((br*128 + ks*64 + lgrp*16) ^ ((br&7)<<4)));
      }
      __builtin_amdgcn_s_setprio(1);
      #pragma unroll
      for (int i=0;i<2;i++)
        #pragma unroll
        for (int j=0;j<4;j++)
          acc[i][j] = __builtin_amdgcn_mfma_f32_16x16x32_bf16(af[i], bfr[j], acc[i][j], 0,0,0);
      __builtin_amdgcn_s_setprio(0);
    }
    cur ^= 1;
  }

  #pragma unroll
  for (int j=0;j<4;j++){
    int n = bn + wn + j*16 + lrow;
    float bv = bias[n];
    #pragma unroll
    for (int i=0;i<2;i++){
      int m0 = bm + wm + i*16 + lgrp*4;
      float v[4];
      #pragma unroll
      for (int r=0;r<4;r++) v[r] = (acc[i][j][r] + bv) * oscale;
      if (MODE == 0){
        u16* o = (u16*)dst;
        int hh = n >> 6, kk = n & 63;
        #pragma unroll
        for (int r=0;r<4;r++) o[((size_t)hh*M + m0 + r)*64 + kk] = f2bf(v[r]);
      } else if (MODE == 1){
        float* o = (float*)dst;
        #pragma unroll
        for (int r=0;r<4;r++) o[(size_t)(m0+r)*N + n] = v[r];
      } else {
        u16* o = (u16*)dst;
        int hh = n >> 6, kk = n & 63;
        ushort4 p; p.x=f2bf(v[0]); p.y=f2bf(v[1]); p.z=f2bf(v[2]); p.w=f2bf(v[3]);
        *reinterpret_cast<ushort4*>(o + ((size_t)hh*64 + kk)*M + m0) = p;
      }
    }
  }
}

// ------- causal flash attention: swapped QK^T (32x32), in-register softmax -------
// P^T -> B-frag goes through a per-wave swizzled LDS bounce (certain-correct path;
// permlane relayout to be re-introduced as an isolated change once this validates).
__global__ __launch_bounds__(128, 2) void flash_attn_kernel(const u16* __restrict__ qb,
                                                            const u16* __restrict__ kb,
                                                            const u16* __restrict__ vtb,
                                                            u16* __restrict__ catb){
  int b = blockIdx.x;
  int h = b & 15;                        // XCD = h&7
  int u = b >> 4;                        // 0..63
  int g = u & 15, qd = u >> 4;
  int ti = (qd==0) ? g : (qd==1) ? 31-g : (qd==2) ? 32+g : 63-g;   // balanced bijection
  int tid = threadIdx.x, wave = tid >> 6, lane = tid & 63;
  int l31 = lane & 31, hi = lane >> 5;
  const u16* qh  = qb  + (size_t)h * S_LEN * 64;
  const u16* kh  = kb  + (size_t)h * S_LEN * 64;
  const u16* vth = vtb + (size_t)h * 64 * S_LEN;

  __shared__ __align__(16) unsigned char lsK[2][8192];
  __shared__ __align__(16) unsigned char lsV[2][8192];
  __shared__ __align__(16) u16 lsP[2][2048];   // per-wave P bounce: 32 q-rows x 64 kv
  unsigned char* Pw = (unsigned char*)lsP[wave];

  int qw = ti*64 + wave*32;              // lane's q-row = qw + l31

  // Q B-fragments: col=q=l31, k = ks*16 + hi*8 + j
  bf16x8 qf[4];
  #pragma unroll
  for (int ks=0;ks<4;ks++)
    qf[ks] = *reinterpret_cast<const bf16x8*>(qh + (size_t)(qw + l31)*64 + ks*16 + hi*8);

  f32x16 oacc0 = {}, oacc1 = {};         // O^T rows d = df*32+(reg&3)+8*(reg>>2)+4*hi, col q=l31
  float m_run = -3e38f, l_run = 0.f;
  int nt = ti + 1;

  auto STAGE = [&](int buf, int jj){
    int kv0 = jj*64;
    #pragma unroll
    for (int c=0;c<8;c++){
      int id = c*128 + tid;              // 0..1023 ; c<4 -> K, else V (uniform per c)
      int r = (id >> 3) & 63;
      int kc = id & 7;
      int cs = (kc ^ (r & 7)) << 3;
      if (id < 512)
        gload_lds16(kh + (size_t)(kv0+r)*64 + cs, lsK[buf] + (id << 4));
      else
        gload_lds16(vth + (size_t)r*S_LEN + kv0 + cs, lsV[buf] + ((id - 512) << 4));
    }
  };

  STAGE(0, 0);
  int cur = 0;
  for (int j = 0; j < nt; j++){
    __syncthreads();
    if (j + 1 < nt) STAGE(cur^1, j + 1);

    bool diag = (j == nt - 1);
    bool f1act = !(diag && wave == 0);   // wave0 diag: kv 32..63 all masked -> skip frag1

    // ---- QK^T (swapped): S^T[kv][q] = K . Q^T ----
    f32x16 s0 = {}, s1 = {};
    __builtin_amdgcn_s_setprio(1);
    #pragma unroll
    for (int ks=0;ks<4;ks++){
      int row = l31;
      bf16x8 kf = *reinterpret_cast<const bf16x8*>(
          lsK[cur] + (row*128 + ((ks*32 + hi*16) ^ ((row&7)<<4))));
      s0 = __builtin_amdgcn_mfma_f32_32x32x16_bf16(kf, qf[ks], s0, 0,0,0);
    }
    if (f1act){
      #pragma unroll
      for (int ks=0;ks<4;ks++){
        int row = 32 + l31;
        bf16x8 kf = *reinterpret_cast<const bf16x8*>(
            lsK[cur] + (row*128 + ((ks*32 + hi*16) ^ ((row&7)<<4))));
        s1 = __builtin_amdgcn_mfma_f32_32x32x16_bf16(kf, qf[ks], s1, 0,0,0);
      }
    }
    __builtin_amdgcn_s_setprio(0);

    // ---- causal mask on diagonal frag (static indexing, no pointer-select) ----
    if (diag){
      if (wave == 0){
        #pragma unroll
        for (int reg=0;reg<16;reg++){
          int kvloc = (reg & 3) + 8*(reg >> 2) + 4*hi;
          if (kvloc > l31) s0[reg] = -3e38f;
        }
      } else {
        #pragma unroll
        for (int reg=0;reg<16;reg++){
          int kvloc = (reg & 3) + 8*(reg >> 2) + 4*hi;
          if (kvloc > l31) s1[reg] = -3e38f;
        }
      }
    }

    // ---- in-register online softmax (exp2 domain; Q pre-scaled) ----
    float mx = -3e38f;
    #pragma unroll
    for (int reg=0;reg<16;reg++) mx = fmaxf(mx, s0[reg]);
    if (f1act){
      #pragma unroll
      for (int reg=0;reg<16;reg++) mx = fmaxf(mx, s1[reg]);
    }
    mx = fmaxf(mx, __shfl_xor(mx, 32));

    if (!__all(mx <= m_run + 11.54f)){   // defer-max (T13)
      float mnew = fmaxf(m_run, mx);
      float al = __builtin_amdgcn_exp2f(m_run - mnew);
      m_run = mnew; l_run *= al;
      #pragma unroll
      for (int reg=0;reg<16;reg++){ oacc0[reg] *= al; oacc1[reg] *= al; }
    }

    float ps = 0.f;
    #pragma unroll
    for (int reg=0;reg<16;reg++){
      float e = __builtin_amdgcn_exp2f(s0[reg] - m_run);
      s0[reg] = e; ps += e;
    }
    if (f1act){
      #pragma unroll
      for (int reg=0;reg<16;reg++){
        float e = __builtin_amdgcn_exp2f(s1[reg] - m_run);
        s1[reg] = e; ps += e;
      }
    }
    ps += __shfl_xor(ps, 32);
    l_run += ps;

    // ---- P bounce: write P[q=l31][kv] to swizzled per-wave LDS ----
    #pragma unroll
    for (int f=0;f<2;f++){
      if (f==1 && !f1act) break;
      #pragma unroll
      for (int m=0;m<4;m++){
        #pragma unroll
        for (int t=0;t<2;t++){
          float plo = f ? s1[4*m+2*t]   : s0[4*m+2*t];
          float phi = f ? s1[4*m+2*t+1] : s0[4*m+2*t+1];
          u32 pk = (u32)f2bf(plo) | ((u32)f2bf(phi) << 16);
          int unit = 4*f + m;            // 16B unit = kv>>3 (kv = 32f+8m+4hi+2t)
          int off = l31*128 + ((unit ^ (l31 & 7)) << 4) + (4*hi + 2*t)*2;
          *reinterpret_cast<u32*>(Pw + off) = pk;
        }
      }
    }

    // ---- PV: O^T += V^T . P^T ----
    __builtin_amdgcn_s_setprio(1);
    #pragma unroll
    for (int f=0;f<2;f++){
      if (f==1 && !f1act) break;
      #pragma unroll
      for (int ksl=0;ksl<2;ksl++){
        int ks = f*2 + ksl;
        bf16x8 pb = *reinterpret_cast<const bf16x8*>(
            Pw + l31*128 + (((2*ks + hi) ^ (l31 & 7)) << 4));
        #pragma unroll
        for (int df=0;df<2;df++){
          int row = df*32 + l31;
          bf16x8 vf = *reinterpret_cast<const bf16x8*>(
              lsV[cur] + (row*128 + ((ks*32 + hi*16) ^ ((row&7)<<4))));
          if (df == 0) oacc0 = __builtin_amdgcn_mfma_f32_32x32x16_bf16(vf, pb, oacc0, 0,0,0);
          else         oacc1 = __builtin_amdgcn_mfma_f32_32x32x16_bf16(vf, pb, oacc1, 0,0,0);
        }
      }
    }
    __builtin_amdgcn_s_setprio(0);
    cur ^= 1;
  }

  // ---- epilogue: catb[q][h*64 + d] = O^T[d][q] / l ----
  float inv = 1.0f / l_run;
  #pragma unroll
  for (int df=0;df<2;df++){
    #pragma unroll
    for (int q4=0;q4<4;q4++){
      int d0 = df*32 + 8*q4 + 4*hi;
      float a0 = (df ? oacc1[q4*4+0] : oacc0[q4*4+0]) * inv;
      float a1 = (df ? oacc1[q4*4+1] : oacc0[q4*4+1]) * inv;
      float a2 = (df ? oacc1[q4*4+2] : oacc0[q4*4+2]) * inv;
      float a3 = (df ? oacc1[q4*4+3] : oacc0[q4*4+3]) * inv;
      ushort4 o;
      o.x = f2bf(a0); o.y = f2bf(a1); o.z = f2bf(a2); o.w = f2bf(a3);
      *reinterpret_cast<ushort4*>(catb + (size_t)(qw + l31)*D_MODEL + h*64 + d0) = o;
    }
  }
}

extern "C" void kernel_launch(void* const* d_in, const int* in_sizes, int n_in,
                              void* d_out, int out_size, void* d_ws, size_t ws_size,
                              hipStream_t stream){
  (void)in_sizes; (void)n_in; (void)out_size; (void)ws_size;
  const float* V  = (const float*)d_in[0];
  const float* Km = (const float*)d_in[1];
  const float* Q  = (const float*)d_in[2];
  const float* WQ = (const float*)d_in[3];
  const float* bQ = (const float*)d_in[4];
  const float* WK = (const float*)d_in[5];
  const float* bK = (const float*)d_in[6];
  const float* WV = (const float*)d_in[7];
  const float* bV = (const float*)d_in[8];
  const float* WO = (const float*)d_in[9];
  const float* bO = (const float*)d_in[10];
  float* out = (float*)d_out;

  char* ws = (char*)d_ws;
  const size_t SZ_SD = (size_t)S_LEN * D_MODEL * 2;
  const size_t SZ_W  = (size_t)D_MODEL * D_MODEL * 2;
  u16* Qb   = (u16*)(ws);
  u16* Kb   = (u16*)(ws + SZ_SD);
  u16* Vb   = (u16*)(ws + 2*SZ_SD);
  u16* WtQ  = (u16*)(ws + 3*SZ_SD);
  u16* WtK  = (u16*)(ws + 3*SZ_SD + SZ_W);
  u16* WtV  = (u16*)(ws + 3*SZ_SD + 2*SZ_W);
  u16* WtO  = (u16*)(ws + 3*SZ_SD + 3*SZ_W);
  u16* qbuf = (u16*)(ws + 3*SZ_SD + 4*SZ_W);
  u16* kbuf = (u16*)(ws + 4*SZ_SD + 4*SZ_W);
  u16* vtb  = (u16*)(ws + 5*SZ_SD + 4*SZ_W);
  u16* catb = (u16*)(ws + 6*SZ_SD + 4*SZ_W);

  const float QSCALE = 0.18033688011112042f;   // 0.125 * log2(e)

  cvt3_kernel<<<dim3(4096,3),256,0,stream>>>(Q, Km, V, Qb, Kb, Vb);
  tcvt_qkv_kernel<<<dim3(16,3,16),256,0,stream>>>(WQ, WK, WV, WtQ, WtK, WtV);
  tcvt_wo_kernel<<<dim3(16,16),256,0,stream>>>(WO, WtO);
  gemm_bt_kernel<0><<<dim3(8,32),512,0,stream>>>(Qb, WtQ, bQ, qbuf, S_LEN, D_MODEL, D_MODEL, QSCALE);
  gemm_bt_kernel<0><<<dim3(8,32),512,0,stream>>>(Kb, WtK, bK, kbuf, S_LEN, D_MODEL, D_MODEL, 1.0f);
  gemm_bt_kernel<2><<<dim3(8,32),512,0,stream>>>(Vb, WtV, bV, vtb, S_LEN, D_MODEL, D_MODEL, 1.0f);
  flash_attn_kernel<<<dim3(1024),128,0,stream>>>(qbuf, kbuf, vtb, catb);
  gemm_bt_kernel<1><<<dim3(8,32),512,0,stream>>>(catb, WtO, bO, out, S_LEN, D_MODEL, D_MODEL, 1.0f);
}

// Round 6
// 177.244 us; speedup vs baseline: 2.1044x; 1.1711x over previous
//
#include <hip/hip_runtime.h>

typedef unsigned short u16;
typedef unsigned int u32;
typedef __attribute__((ext_vector_type(8))) __bf16 bf16x8;
typedef __attribute__((ext_vector_type(4))) float f32x4;
typedef __attribute__((ext_vector_type(16))) float f32x16;

#define S_LEN 4096
#define D_MODEL 1024
#define NH 16
#define DHEAD 64

__device__ __forceinline__ u16 f2bf(float f){
  unsigned u = __float_as_uint(f);
  u += 0x7FFFu + ((u >> 16) & 1u);   // RTNE
  return (u16)(u >> 16);
}

__device__ __forceinline__ void gload_lds16(const void* g, void* l){
  __builtin_amdgcn_global_load_lds((const __attribute__((address_space(1))) void*)g,
                                   (__attribute__((address_space(3))) void*)l, 16, 0, 0);
}

// ---------------- fp32 -> bf16, three tensors in one launch ----------------
__global__ __launch_bounds__(256) void cvt3_kernel(const float* __restrict__ q,
                                                   const float* __restrict__ k,
                                                   const float* __restrict__ v,
                                                   u16* __restrict__ oq,
                                                   u16* __restrict__ ok,
                                                   u16* __restrict__ ov){
  int z = blockIdx.y;
  const float* in = (z==0)? q : (z==1)? k : v;
  u16* out = (z==0)? oq : (z==1)? ok : ov;
  int i = blockIdx.x*256 + threadIdx.x;
  float4 w = reinterpret_cast<const float4*>(in)[i];
  ushort4 o;
  o.x = f2bf(w.x); o.y = f2bf(w.y); o.z = f2bf(w.z); o.w = f2bf(w.w);
  reinterpret_cast<ushort4*>(out)[i] = o;
}

// ------- transpose+convert QKV weights: [16][1024][64] fp32 -> [16][64][1024] bf16 -------
__global__ __launch_bounds__(256) void tcvt_qkv_kernel(const float* __restrict__ wq,
                                                       const float* __restrict__ wk,
                                                       const float* __restrict__ wv,
                                                       u16* __restrict__ oq,
                                                       u16* __restrict__ ok,
                                                       u16* __restrict__ ov){
  int which = blockIdx.y;
  const float* in = (which==0)? wq : (which==1)? wk : wv;
  u16* out = (which==0)? oq : (which==1)? ok : ov;
  __shared__ float tile[64][67];
  int z = blockIdx.z;
  const float* inh = in + (size_t)z*1024*64;
  u16* outh = out + (size_t)z*1024*64;
  int tid = threadIdx.x;
  int r0 = blockIdx.x*64;
  #pragma unroll
  for (int c=0;c<4;c++){
    int cl = c*256 + tid;
    int row = cl >> 4, cc = (cl & 15) * 4;
    float4 v = *reinterpret_cast<const float4*>(inh + (size_t)(r0+row)*64 + cc);
    tile[row][cc+0]=v.x; tile[row][cc+1]=v.y; tile[row][cc+2]=v.z; tile[row][cc+3]=v.w;
  }
  __syncthreads();
  #pragma unroll
  for (int c=0;c<4;c++){
    int cl = c*256 + tid;
    int crow = cl >> 4, rc = (cl & 15) * 4;
    ushort4 o;
    o.x = f2bf(tile[rc+0][crow]);
    o.y = f2bf(tile[rc+1][crow]);
    o.z = f2bf(tile[rc+2][crow]);
    o.w = f2bf(tile[rc+3][crow]);
    *reinterpret_cast<ushort4*>(outh + (size_t)crow*1024 + r0 + rc) = o;
  }
}

// ------- transpose+convert WO: [1024][1024] fp32 -> WO^T bf16 -------
__global__ __launch_bounds__(256) void tcvt_wo_kernel(const float* __restrict__ in,
                                                      u16* __restrict__ out){
  __shared__ float tile[64][67];
  int r0 = blockIdx.x*64, c0 = blockIdx.y*64;
  int tid = threadIdx.x;
  #pragma unroll
  for (int c=0;c<4;c++){
    int cl = c*256 + tid;
    int row = cl >> 4, cc = (cl & 15) * 4;
    float4 v = *reinterpret_cast<const float4*>(in + (size_t)(r0+row)*1024 + c0 + cc);
    tile[row][cc+0]=v.x; tile[row][cc+1]=v.y; tile[row][cc+2]=v.z; tile[row][cc+3]=v.w;
  }
  __syncthreads();
  #pragma unroll
  for (int c=0;c<4;c++){
    int cl = c*256 + tid;
    int crow = cl >> 4, rc = (cl & 15) * 4;
    ushort4 o;
    o.x = f2bf(tile[rc+0][crow]);
    o.y = f2bf(tile[rc+1][crow]);
    o.z = f2bf(tile[rc+2][crow]);
    o.w = f2bf(tile[rc+3][crow]);
    *reinterpret_cast<ushort4*>(out + (size_t)(c0+crow)*1024 + r0 + rc) = o;
  }
}

// ------- fused QKV projection GEMM: z selects {Q,K,V} ; 8 waves, 128x128 tile -------
// z=0,1: bf16 -> [H][S][64] ; z=2: bf16 -> [H][64][S] (V^T)
__global__ __launch_bounds__(512) void gemm_qkv_kernel(
    const u16* __restrict__ Qb, const u16* __restrict__ Kb, const u16* __restrict__ Vb,
    const u16* __restrict__ WtQ, const u16* __restrict__ WtK, const u16* __restrict__ WtV,
    const float* __restrict__ bQ, const float* __restrict__ bK, const float* __restrict__ bV,
    u16* __restrict__ qbuf, u16* __restrict__ kbuf, u16* __restrict__ vtb, float qscale){
  const int M = S_LEN, N = D_MODEL, K = D_MODEL;
  int z = blockIdx.z;
  const u16* A  = (z==0)? Qb  : (z==1)? Kb  : Vb;
  const u16* Bt = (z==0)? WtQ : (z==1)? WtK : WtV;
  const float* bias = (z==0)? bQ : (z==1)? bK : bV;
  float oscale = (z==0)? qscale : 1.0f;

  __shared__ __align__(16) unsigned char lsA[2][16384];
  __shared__ __align__(16) unsigned char lsB[2][16384];
  int tid = threadIdx.x;
  int bm = blockIdx.y * 128, bn = blockIdx.x * 128;
  int wave = tid >> 6, lane = tid & 63;
  int wm = (wave >> 1) * 32, wn = (wave & 1) * 64;
  int lrow = lane & 15, lgrp = lane >> 4;

  f32x4 acc[2][4] = {};

  auto STAGE = [&](int buf, int k0){
    #pragma unroll
    for (int c=0;c<4;c++){
      int id = c*512 + tid;
      int r = (id & 1023) >> 3;
      int kc = id & 7;
      int cs = (kc ^ (r & 7)) << 3;
      if (id < 1024)
        gload_lds16(A + (size_t)(bm+r)*K + k0 + cs, lsA[buf] + ((id & 1023) << 4));
      else
        gload_lds16(Bt + (size_t)(bn+r)*K + k0 + cs, lsB[buf] + ((id & 1023) << 4));
    }
  };

  STAGE(0, 0);
  int cur = 0;
  for (int k0 = 0; k0 < K; k0 += 64){
    __syncthreads();
    if (k0 + 64 < K) STAGE(cur^1, k0 + 64);
    #pragma unroll
    for (int ks=0;ks<2;ks++){
      bf16x8 af[2], bfr[4];
      #pragma unroll
      for (int i=0;i<2;i++){
        int ar = wm + i*16 + lrow;
        af[i] = *reinterpret_cast<const bf16x8*>(lsA[cur] + ((ar*128 + ks*64 + lgrp*16) ^ ((ar&7)<<4)));
      }
      #pragma unroll
      for (int j=0;j<4;j++){
        int br = wn + j*16 + lrow;
        bfr[j] = *reinterpret_cast<const bf16x8*>(lsB[cur] + ((br*128 + ks*64 + lgrp*16) ^ ((br&7)<<4)));
      }
      __builtin_amdgcn_s_setprio(1);
      #pragma unroll
      for (int i=0;i<2;i++)
        #pragma unroll
        for (int j=0;j<4;j++)
          acc[i][j] = __builtin_amdgcn_mfma_f32_16x16x32_bf16(af[i], bfr[j], acc[i][j], 0,0,0);
      __builtin_amdgcn_s_setprio(0);
    }
    cur ^= 1;
  }

  #pragma unroll
  for (int j=0;j<4;j++){
    int n = bn + wn + j*16 + lrow;
    float bv = bias[n];
    int hh = n >> 6, kk = n & 63;
    #pragma unroll
    for (int i=0;i<2;i++){
      int m0 = bm + wm + i*16 + lgrp*4;
      float v[4];
      #pragma unroll
      for (int r=0;r<4;r++) v[r] = (acc[i][j][r] + bv) * oscale;
      if (z < 2){
        u16* o = (z==0)? qbuf : kbuf;
        #pragma unroll
        for (int r=0;r<4;r++) o[((size_t)hh*M + m0 + r)*64 + kk] = f2bf(v[r]);
      } else {
        ushort4 p; p.x=f2bf(v[0]); p.y=f2bf(v[1]); p.z=f2bf(v[2]); p.w=f2bf(v[3]);
        *reinterpret_cast<ushort4*>(vtb + ((size_t)hh*64 + kk)*M + m0) = p;
      }
    }
  }
}

// ------- output GEMM: fp32 [M][N] -------
__global__ __launch_bounds__(512) void gemm_out_kernel(const u16* __restrict__ A,
                                                       const u16* __restrict__ Bt,
                                                       const float* __restrict__ bias,
                                                       float* __restrict__ dst,
                                                       int M, int N, int K){
  __shared__ __align__(16) unsigned char lsA[2][16384];
  __shared__ __align__(16) unsigned char lsB[2][16384];
  int tid = threadIdx.x;
  int bm = blockIdx.y * 128, bn = blockIdx.x * 128;
  int wave = tid >> 6, lane = tid & 63;
  int wm = (wave >> 1) * 32, wn = (wave & 1) * 64;
  int lrow = lane & 15, lgrp = lane >> 4;

  f32x4 acc[2][4] = {};

  auto STAGE = [&](int buf, int k0){
    #pragma unroll
    for (int c=0;c<4;c++){
      int id = c*512 + tid;
      int r = (id & 1023) >> 3;
      int kc = id & 7;
      int cs = (kc ^ (r & 7)) << 3;
      if (id < 1024)
        gload_lds16(A + (size_t)(bm+r)*K + k0 + cs, lsA[buf] + ((id & 1023) << 4));
      else
        gload_lds16(Bt + (size_t)(bn+r)*K + k0 + cs, lsB[buf] + ((id & 1023) << 4));
    }
  };

  STAGE(0, 0);
  int cur = 0;
  for (int k0 = 0; k0 < K; k0 += 64){
    __syncthreads();
    if (k0 + 64 < K) STAGE(cur^1, k0 + 64);
    #pragma unroll
    for (int ks=0;ks<2;ks++){
      bf16x8 af[2], bfr[4];
      #pragma unroll
      for (int i=0;i<2;i++){
        int ar = wm + i*16 + lrow;
        af[i] = *reinterpret_cast<const bf16x8*>(lsA[cur] + ((ar*128 + ks*64 + lgrp*16) ^ ((ar&7)<<4)));
      }
      #pragma unroll
      for (int j=0;j<4;j++){
        int br = wn + j*16 + lrow;
        bfr[j] = *reinterpret_cast<const bf16x8*>(lsB[cur] + ((br*128 + ks*64 + lgrp*16) ^ ((br&7)<<4)));
      }
      __builtin_amdgcn_s_setprio(1);
      #pragma unroll
      for (int i=0;i<2;i++)
        #pragma unroll
        for (int j=0;j<4;j++)
          acc[i][j] = __builtin_amdgcn_mfma_f32_16x16x32_bf16(af[i], bfr[j], acc[i][j], 0,0,0);
      __builtin_amdgcn_s_setprio(0);
    }
    cur ^= 1;
  }

  #pragma unroll
  for (int j=0;j<4;j++){
    int n = bn + wn + j*16 + lrow;
    float bv = bias[n];
    #pragma unroll
    for (int i=0;i<2;i++){
      int m0 = bm + wm + i*16 + lgrp*4;
      #pragma unroll
      for (int r=0;r<4;r++) dst[(size_t)(m0+r)*N + n] = acc[i][j][r] + bv;
    }
  }
}

// ------- causal flash attention, KV-halved: block = (h, qtile, half) -------
// qb (pre-scaled by 0.125*log2e), kb: [H][S][64] ; vtb: [H][64][S] (bf16)
// partials: pO bf16 [2][H][16 dquad][S][4], pml float2 [2][H][S]
__global__ __launch_bounds__(128, 2) void flash_attn_kernel(const u16* __restrict__ qb,
                                                            const u16* __restrict__ kb,
                                                            const u16* __restrict__ vtb,
                                                            u16* __restrict__ pO,
                                                            float2* __restrict__ pml){
  int b = blockIdx.x;
  int h = b & 15;                        // XCD = h&7 -> per-XCD L2 locality
  int u = b >> 4;                        // 0..127
  int qt = u >> 1, half = u & 1;
  int nt = qt + 1;
  int jmid = (nt + 1) >> 1;
  int j0 = half ? jmid : 0;
  int j1 = half ? nt : jmid;

  int tid = threadIdx.x, wave = tid >> 6, lane = tid & 63;
  int l31 = lane & 31, hi = lane >> 5;
  const u16* qh  = qb  + (size_t)h * S_LEN * 64;
  const u16* kh  = kb  + (size_t)h * S_LEN * 64;
  const u16* vth = vtb + (size_t)h * 64 * S_LEN;

  __shared__ __align__(16) unsigned char lsK[2][8192];
  __shared__ __align__(16) unsigned char lsV[2][8192];
  __shared__ __align__(16) u16 lsP[2][2048];   // per-wave P bounce
  unsigned char* Pw = (unsigned char*)lsP[wave];

  int qw = qt*64 + wave*32;              // lane's q-row = qw + l31

  bf16x8 qf[4];
  #pragma unroll
  for (int ks=0;ks<4;ks++)
    qf[ks] = *reinterpret_cast<const bf16x8*>(qh + (size_t)(qw + l31)*64 + ks*16 + hi*8);

  f32x16 oacc0 = {}, oacc1 = {};         // O^T rows d = df*32+(reg&3)+8*(reg>>2)+4hi, col q=l31
  float m_run = -3e38f, l_run = 0.f;

  auto STAGE = [&](int buf, int jj){
    int kv0 = jj*64;
    #pragma unroll
    for (int c=0;c<8;c++){
      int id = c*128 + tid;              // 0..1023 ; c<4 -> K, else V (uniform per c)
      int r = (id >> 3) & 63;
      int kc = id & 7;
      int cs = (kc ^ (r & 7)) << 3;
      if (id < 512)
        gload_lds16(kh + (size_t)(kv0+r)*64 + cs, lsK[buf] + (id << 4));
      else
        gload_lds16(vth + (size_t)r*S_LEN + kv0 + cs, lsV[buf] + ((id - 512) << 4));
    }
  };

  if (j0 < j1) STAGE(0, j0);
  int cur = 0;
  for (int j = j0; j < j1; j++){
    __syncthreads();
    if (j + 1 < j1) STAGE(cur^1, j + 1);

    bool diag = (j == nt - 1);
    bool f1act = !(diag && wave == 0);   // wave0 diag: kv 32..63 all masked -> skip frag1

    // ---- QK^T (swapped): S^T[kv][q] = K . Q^T ----
    f32x16 s0 = {}, s1 = {};
    __builtin_amdgcn_s_setprio(1);
    #pragma unroll
    for (int ks=0;ks<4;ks++){
      int row = l31;
      bf16x8 kf = *reinterpret_cast<const bf16x8*>(
          lsK[cur] + (row*128 + ((ks*32 + hi*16) ^ ((row&7)<<4))));
      s0 = __builtin_amdgcn_mfma_f32_32x32x16_bf16(kf, qf[ks], s0, 0,0,0);
    }
    if (f1act){
      #pragma unroll
      for (int ks=0;ks<4;ks++){
        int row = 32 + l31;
        bf16x8 kf = *reinterpret_cast<const bf16x8*>(
            lsK[cur] + (row*128 + ((ks*32 + hi*16) ^ ((row&7)<<4))));
        s1 = __builtin_amdgcn_mfma_f32_32x32x16_bf16(kf, qf[ks], s1, 0,0,0);
      }
    }
    __builtin_amdgcn_s_setprio(0);

    // ---- causal mask on diagonal frag ----
    if (diag){
      if (wave == 0){
        #pragma unroll
        for (int reg=0;reg<16;reg++){
          int kvloc = (reg & 3) + 8*(reg >> 2) + 4*hi;
          if (kvloc > l31) s0[reg] = -3e38f;
        }
      } else {
        #pragma unroll
        for (int reg=0;reg<16;reg++){
          int kvloc = (reg & 3) + 8*(reg >> 2) + 4*hi;
          if (kvloc > l31) s1[reg] = -3e38f;
        }
      }
    }

    // ---- in-register online softmax (exp2 domain; Q pre-scaled) ----
    float mx = -3e38f;
    #pragma unroll
    for (int reg=0;reg<16;reg++) mx = fmaxf(mx, s0[reg]);
    if (f1act){
      #pragma unroll
      for (int reg=0;reg<16;reg++) mx = fmaxf(mx, s1[reg]);
    }
    mx = fmaxf(mx, __shfl_xor(mx, 32));

    if (!__all(mx <= m_run + 11.54f)){   // defer-max (T13)
      float mnew = fmaxf(m_run, mx);
      float al = __builtin_amdgcn_exp2f(m_run - mnew);
      m_run = mnew; l_run *= al;
      #pragma unroll
      for (int reg=0;reg<16;reg++){ oacc0[reg] *= al; oacc1[reg] *= al; }
    }

    float ps = 0.f;
    #pragma unroll
    for (int reg=0;reg<16;reg++){
      float e = __builtin_amdgcn_exp2f(s0[reg] - m_run);
      s0[reg] = e; ps += e;
    }
    if (f1act){
      #pragma unroll
      for (int reg=0;reg<16;reg++){
        float e = __builtin_amdgcn_exp2f(s1[reg] - m_run);
        s1[reg] = e; ps += e;
      }
    }
    ps += __shfl_xor(ps, 32);
    l_run += ps;

    // ---- P bounce: cvt_pk pack + conflict-free ds_write_b64 ----
    #pragma unroll
    for (int f=0;f<2;f++){
      if (f==1 && !f1act) break;
      #pragma unroll
      for (int m=0;m<4;m++){
        float b0 = f ? s1[4*m+0] : s0[4*m+0];
        float b1 = f ? s1[4*m+1] : s0[4*m+1];
        float b2 = f ? s1[4*m+2] : s0[4*m+2];
        float b3 = f ? s1[4*m+3] : s0[4*m+3];
        u32 w0p, w1p;
        asm("v_cvt_pk_bf16_f32 %0, %1, %2" : "=v"(w0p) : "v"(b0), "v"(b1));
        asm("v_cvt_pk_bf16_f32 %0, %1, %2" : "=v"(w1p) : "v"(b2), "v"(b3));
        int unit = 4*f + m;
        int off = l31*128 + ((unit ^ (l31 & 7)) << 4) + hi*8;
        uint2 pv; pv.x = w0p; pv.y = w1p;
        *reinterpret_cast<uint2*>(Pw + off) = pv;
      }
    }

    // ---- PV: O^T += V^T . P^T ----
    __builtin_amdgcn_s_setprio(1);
    #pragma unroll
    for (int f=0;f<2;f++){
      if (f==1 && !f1act) break;
      #pragma unroll
      for (int ksl=0;ksl<2;ksl++){
        int ks = f*2 + ksl;
        bf16x8 pb = *reinterpret_cast<const bf16x8*>(
            Pw + l31*128 + (((2*ks + hi) ^ (l31 & 7)) << 4));
        #pragma unroll
        for (int df=0;df<2;df++){
          int row = df*32 + l31;
          bf16x8 vf = *reinterpret_cast<const bf16x8*>(
              lsV[cur] + (row*128 + ((ks*32 + hi*16) ^ ((row&7)<<4))));
          if (df == 0) oacc0 = __builtin_amdgcn_mfma_f32_32x32x16_bf16(vf, pb, oacc0, 0,0,0);
          else         oacc1 = __builtin_amdgcn_mfma_f32_32x32x16_bf16(vf, pb, oacc1, 0,0,0);
        }
      }
    }
    __builtin_amdgcn_s_setprio(0);
    cur ^= 1;
  }

  // ---- epilogue: write partial (m, l, unnormalized O as bf16) ----
  int q = qw + l31;
  if (hi == 0){
    float2 ml; ml.x = m_run; ml.y = l_run;
    pml[((size_t)half*NH + h)*S_LEN + q] = ml;
  }
  #pragma unroll
  for (int df=0;df<2;df++){
    #pragma unroll
    for (int q4=0;q4<4;q4++){
      float a0 = df ? oacc1[4*q4+0] : oacc0[4*q4+0];
      float a1 = df ? oacc1[4*q4+1] : oacc0[4*q4+1];
      float a2 = df ? oacc1[4*q4+2] : oacc0[4*q4+2];
      float a3 = df ? oacc1[4*q4+3] : oacc0[4*q4+3];
      u32 w0d, w1d;
      asm("v_cvt_pk_bf16_f32 %0, %1, %2" : "=v"(w0d) : "v"(a0), "v"(a1));
      asm("v_cvt_pk_bf16_f32 %0, %1, %2" : "=v"(w1d) : "v"(a2), "v"(a3));
      int dquad = df*8 + 2*q4 + hi;      // d/4 for d = df*32 + 8*q4 + 4*hi
      uint2 pv; pv.x = w0d; pv.y = w1d;
      *reinterpret_cast<uint2*>(pO + (((size_t)(half*NH + h)*16 + dquad)*S_LEN + q)*4) = pv;
    }
  }
}

// ------- combine two KV-half partials -> catb bf16 [S][1024] -------
__global__ __launch_bounds__(256) void combine_kernel(const u16* __restrict__ pO,
                                                      const float2* __restrict__ pml,
                                                      u16* __restrict__ catb){
  int tid = threadIdx.x;
  int dq = tid & 15, qo = tid >> 4;
  int h = blockIdx.y;
  int q = blockIdx.x*16 + qo;
  float2 ml0 = pml[(size_t)h*S_LEN + q];
  float2 ml1 = pml[(size_t)(NH + h)*S_LEN + q];
  float m = fmaxf(ml0.x, ml1.x);
  float w0 = __builtin_amdgcn_exp2f(ml0.x - m);
  float w1 = __builtin_amdgcn_exp2f(ml1.x - m);
  float inv = 1.0f / (w0*ml0.y + w1*ml1.y);
  size_t i0 = ((size_t)h*16 + dq)*S_LEN + q;
  size_t i1 = (size_t)NH*16*S_LEN + i0;
  ushort4 a = reinterpret_cast<const ushort4*>(pO)[i0];
  ushort4 b = reinterpret_cast<const ushort4*>(pO)[i1];
  ushort4 o;
  float x0 = __uint_as_float((u32)a.x << 16)*w0 + __uint_as_float((u32)b.x << 16)*w1;
  float x1 = __uint_as_float((u32)a.y << 16)*w0 + __uint_as_float((u32)b.y << 16)*w1;
  float x2 = __uint_as_float((u32)a.z << 16)*w0 + __uint_as_float((u32)b.z << 16)*w1;
  float x3 = __uint_as_float((u32)a.w << 16)*w0 + __uint_as_float((u32)b.w << 16)*w1;
  o.x = f2bf(x0*inv); o.y = f2bf(x1*inv); o.z = f2bf(x2*inv); o.w = f2bf(x3*inv);
  *reinterpret_cast<ushort4*>(catb + (size_t)q*D_MODEL + h*64 + dq*4) = o;
}

extern "C" void kernel_launch(void* const* d_in, const int* in_sizes, int n_in,
                              void* d_out, int out_size, void* d_ws, size_t ws_size,
                              hipStream_t stream){
  (void)in_sizes; (void)n_in; (void)out_size; (void)ws_size;
  const float* V  = (const float*)d_in[0];
  const float* Km = (const float*)d_in[1];
  const float* Q  = (const float*)d_in[2];
  const float* WQ = (const float*)d_in[3];
  const float* bQ = (const float*)d_in[4];
  const float* WK = (const float*)d_in[5];
  const float* bK = (const float*)d_in[6];
  const float* WV = (const float*)d_in[7];
  const float* bV = (const float*)d_in[8];
  const float* WO = (const float*)d_in[9];
  const float* bO = (const float*)d_in[10];
  float* out = (float*)d_out;

  char* ws = (char*)d_ws;
  const size_t SZ_SD = (size_t)S_LEN * D_MODEL * 2;    // 8 MiB
  const size_t SZ_W  = (size_t)D_MODEL * D_MODEL * 2;  // 2 MiB
  u16* Qb   = (u16*)(ws);
  u16* Kb   = (u16*)(ws + SZ_SD);
  u16* Vb   = (u16*)(ws + 2*SZ_SD);
  u16* WtQ  = (u16*)(ws + 3*SZ_SD);
  u16* WtK  = (u16*)(ws + 3*SZ_SD + SZ_W);
  u16* WtV  = (u16*)(ws + 3*SZ_SD + 2*SZ_W);
  u16* WtO  = (u16*)(ws + 3*SZ_SD + 3*SZ_W);
  u16* qbuf = (u16*)(ws + 3*SZ_SD + 4*SZ_W);
  u16* kbuf = (u16*)(ws + 4*SZ_SD + 4*SZ_W);
  u16* vtb  = (u16*)(ws + 5*SZ_SD + 4*SZ_W);
  u16* catb = (u16*)(ws + 6*SZ_SD + 4*SZ_W);
  u16* pO   = (u16*)(ws + 7*SZ_SD + 4*SZ_W);           // 16 MiB: [2][16][16][4096][4] u16
  float2* pml = (float2*)(ws + 9*SZ_SD + 4*SZ_W);      // 1 MiB: [2][16][4096] float2
  // total: 9*SZ_SD + 4*SZ_W + 17MB ~= 97 MiB

  const float QSCALE = 0.18033688011112042f;   // 0.125 * log2(e)

  cvt3_kernel<<<dim3(4096,3),256,0,stream>>>(Q, Km, V, Qb, Kb, Vb);
  tcvt_qkv_kernel<<<dim3(16,3,16),256,0,stream>>>(WQ, WK, WV, WtQ, WtK, WtV);
  tcvt_wo_kernel<<<dim3(16,16),256,0,stream>>>(WO, WtO);
  gemm_qkv_kernel<<<dim3(8,32,3),512,0,stream>>>(Qb, Kb, Vb, WtQ, WtK, WtV,
                                                 bQ, bK, bV, qbuf, kbuf, vtb, QSCALE);
  flash_attn_kernel<<<dim3(2048),128,0,stream>>>(qbuf, kbuf, vtb, pO, pml);
  combine_kernel<<<dim3(256,16),256,0,stream>>>(pO, pml, catb);
  gemm_out_kernel<<<dim3(8,32),512,0,stream>>>(catb, WtO, bO, out, S_LEN, D_MODEL, D_MODEL);
}

// Round 7
// 162.233 us; speedup vs baseline: 2.2991x; 1.0925x over previous
//
#include <hip/hip_runtime.h>

typedef unsigned short u16;
typedef unsigned int u32;
typedef __attribute__((ext_vector_type(8))) __bf16 bf16x8;
typedef __attribute__((ext_vector_type(4))) float f32x4;
typedef __attribute__((ext_vector_type(16))) float f32x16;

#define S_LEN 4096
#define D_MODEL 1024
#define NH 16
#define DHEAD 64

__device__ __forceinline__ u16 f2bf(float f){
  unsigned u = __float_as_uint(f);
  u += 0x7FFFu + ((u >> 16) & 1u);   // RTNE
  return (u16)(u >> 16);
}

__device__ __forceinline__ void gload_lds16(const void* g, void* l){
  __builtin_amdgcn_global_load_lds((const __attribute__((address_space(1))) void*)g,
                                   (__attribute__((address_space(3))) void*)l, 16, 0, 0);
}

// ---------------- fp32 -> bf16, three tensors in one launch ----------------
__global__ __launch_bounds__(256) void cvt3_kernel(const float* __restrict__ q,
                                                   const float* __restrict__ k,
                                                   const float* __restrict__ v,
                                                   u16* __restrict__ oq,
                                                   u16* __restrict__ ok,
                                                   u16* __restrict__ ov){
  int z = blockIdx.y;
  const float* in = (z==0)? q : (z==1)? k : v;
  u16* out = (z==0)? oq : (z==1)? ok : ov;
  int i = blockIdx.x*256 + threadIdx.x;
  float4 w = reinterpret_cast<const float4*>(in)[i];
  ushort4 o;
  o.x = f2bf(w.x); o.y = f2bf(w.y); o.z = f2bf(w.z); o.w = f2bf(w.w);
  reinterpret_cast<ushort4*>(out)[i] = o;
}

// ------- transpose+convert QKV weights: [16][1024][64] fp32 -> [16][64][1024] bf16 -------
__global__ __launch_bounds__(256) void tcvt_qkv_kernel(const float* __restrict__ wq,
                                                       const float* __restrict__ wk,
                                                       const float* __restrict__ wv,
                                                       u16* __restrict__ oq,
                                                       u16* __restrict__ ok,
                                                       u16* __restrict__ ov){
  int which = blockIdx.y;
  const float* in = (which==0)? wq : (which==1)? wk : wv;
  u16* out = (which==0)? oq : (which==1)? ok : ov;
  __shared__ float tile[64][67];
  int z = blockIdx.z;
  const float* inh = in + (size_t)z*1024*64;
  u16* outh = out + (size_t)z*1024*64;
  int tid = threadIdx.x;
  int r0 = blockIdx.x*64;
  #pragma unroll
  for (int c=0;c<4;c++){
    int cl = c*256 + tid;
    int row = cl >> 4, cc = (cl & 15) * 4;
    float4 v = *reinterpret_cast<const float4*>(inh + (size_t)(r0+row)*64 + cc);
    tile[row][cc+0]=v.x; tile[row][cc+1]=v.y; tile[row][cc+2]=v.z; tile[row][cc+3]=v.w;
  }
  __syncthreads();
  #pragma unroll
  for (int c=0;c<4;c++){
    int cl = c*256 + tid;
    int crow = cl >> 4, rc = (cl & 15) * 4;
    ushort4 o;
    o.x = f2bf(tile[rc+0][crow]);
    o.y = f2bf(tile[rc+1][crow]);
    o.z = f2bf(tile[rc+2][crow]);
    o.w = f2bf(tile[rc+3][crow]);
    *reinterpret_cast<ushort4*>(outh + (size_t)crow*1024 + r0 + rc) = o;
  }
}

// ------- transpose+convert WO: [1024][1024] fp32 -> WO^T bf16 -------
__global__ __launch_bounds__(256) void tcvt_wo_kernel(const float* __restrict__ in,
                                                      u16* __restrict__ out){
  __shared__ float tile[64][67];
  int r0 = blockIdx.x*64, c0 = blockIdx.y*64;
  int tid = threadIdx.x;
  #pragma unroll
  for (int c=0;c<4;c++){
    int cl = c*256 + tid;
    int row = cl >> 4, cc = (cl & 15) * 4;
    float4 v = *reinterpret_cast<const float4*>(in + (size_t)(r0+row)*1024 + c0 + cc);
    tile[row][cc+0]=v.x; tile[row][cc+1]=v.y; tile[row][cc+2]=v.z; tile[row][cc+3]=v.w;
  }
  __syncthreads();
  #pragma unroll
  for (int c=0;c<4;c++){
    int cl = c*256 + tid;
    int crow = cl >> 4, rc = (cl & 15) * 4;
    ushort4 o;
    o.x = f2bf(tile[rc+0][crow]);
    o.y = f2bf(tile[rc+1][crow]);
    o.z = f2bf(tile[rc+2][crow]);
    o.w = f2bf(tile[rc+3][crow]);
    *reinterpret_cast<ushort4*>(out + (size_t)(c0+crow)*1024 + r0 + rc) = o;
  }
}

// ------- fused QKV projection GEMM: z selects {Q,K,V} ; 8 waves, 128x128 tile -------
// z=0,1: bf16 -> [H][S][64] ; z=2: bf16 -> [H][64][S] (V^T)
__global__ __launch_bounds__(512) void gemm_qkv_kernel(
    const u16* __restrict__ Qb, const u16* __restrict__ Kb, const u16* __restrict__ Vb,
    const u16* __restrict__ WtQ, const u16* __restrict__ WtK, const u16* __restrict__ WtV,
    const float* __restrict__ bQ, const float* __restrict__ bK, const float* __restrict__ bV,
    u16* __restrict__ qbuf, u16* __restrict__ kbuf, u16* __restrict__ vtb, float qscale){
  const int M = S_LEN, N = D_MODEL, K = D_MODEL;
  int z = blockIdx.z;
  const u16* A  = (z==0)? Qb  : (z==1)? Kb  : Vb;
  const u16* Bt = (z==0)? WtQ : (z==1)? WtK : WtV;
  const float* bias = (z==0)? bQ : (z==1)? bK : bV;
  float oscale = (z==0)? qscale : 1.0f;

  __shared__ __align__(16) unsigned char lsA[2][16384];
  __shared__ __align__(16) unsigned char lsB[2][16384];
  int tid = threadIdx.x;
  int bm = blockIdx.y * 128, bn = blockIdx.x * 128;
  int wave = tid >> 6, lane = tid & 63;
  int wm = (wave >> 1) * 32, wn = (wave & 1) * 64;
  int lrow = lane & 15, lgrp = lane >> 4;

  f32x4 acc[2][4] = {};

  auto STAGE = [&](int buf, int k0){
    #pragma unroll
    for (int c=0;c<4;c++){
      int id = c*512 + tid;
      int r = (id & 1023) >> 3;
      int kc = id & 7;
      int cs = (kc ^ (r & 7)) << 3;
      if (id < 1024)
        gload_lds16(A + (size_t)(bm+r)*K + k0 + cs, lsA[buf] + ((id & 1023) << 4));
      else
        gload_lds16(Bt + (size_t)(bn+r)*K + k0 + cs, lsB[buf] + ((id & 1023) << 4));
    }
  };

  STAGE(0, 0);
  int cur = 0;
  for (int k0 = 0; k0 < K; k0 += 64){
    __syncthreads();
    if (k0 + 64 < K) STAGE(cur^1, k0 + 64);
    #pragma unroll
    for (int ks=0;ks<2;ks++){
      bf16x8 af[2], bfr[4];
      #pragma unroll
      for (int i=0;i<2;i++){
        int ar = wm + i*16 + lrow;
        af[i] = *reinterpret_cast<const bf16x8*>(lsA[cur] + ((ar*128 + ks*64 + lgrp*16) ^ ((ar&7)<<4)));
      }
      #pragma unroll
      for (int j=0;j<4;j++){
        int br = wn + j*16 + lrow;
        bfr[j] = *reinterpret_cast<const bf16x8*>(lsB[cur] + ((br*128 + ks*64 + lgrp*16) ^ ((br&7)<<4)));
      }
      __builtin_amdgcn_s_setprio(1);
      #pragma unroll
      for (int i=0;i<2;i++)
        #pragma unroll
        for (int j=0;j<4;j++)
          acc[i][j] = __builtin_amdgcn_mfma_f32_16x16x32_bf16(af[i], bfr[j], acc[i][j], 0,0,0);
      __builtin_amdgcn_s_setprio(0);
    }
    cur ^= 1;
  }

  #pragma unroll
  for (int j=0;j<4;j++){
    int n = bn + wn + j*16 + lrow;
    float bv = bias[n];
    int hh = n >> 6, kk = n & 63;
    #pragma unroll
    for (int i=0;i<2;i++){
      int m0 = bm + wm + i*16 + lgrp*4;
      float v[4];
      #pragma unroll
      for (int r=0;r<4;r++) v[r] = (acc[i][j][r] + bv) * oscale;
      if (z < 2){
        u16* o = (z==0)? qbuf : kbuf;
        #pragma unroll
        for (int r=0;r<4;r++) o[((size_t)hh*M + m0 + r)*64 + kk] = f2bf(v[r]);
      } else {
        ushort4 p; p.x=f2bf(v[0]); p.y=f2bf(v[1]); p.z=f2bf(v[2]); p.w=f2bf(v[3]);
        *reinterpret_cast<ushort4*>(vtb + ((size_t)hh*64 + kk)*M + m0) = p;
      }
    }
  }
}

// ------- output GEMM: fp32 [M][N] -------
__global__ __launch_bounds__(512) void gemm_out_kernel(const u16* __restrict__ A,
                                                       const u16* __restrict__ Bt,
                                                       const float* __restrict__ bias,
                                                       float* __restrict__ dst,
                                                       int M, int N, int K){
  __shared__ __align__(16) unsigned char lsA[2][16384];
  __shared__ __align__(16) unsigned char lsB[2][16384];
  int tid = threadIdx.x;
  int bm = blockIdx.y * 128, bn = blockIdx.x * 128;
  int wave = tid >> 6, lane = tid & 63;
  int wm = (wave >> 1) * 32, wn = (wave & 1) * 64;
  int lrow = lane & 15, lgrp = lane >> 4;

  f32x4 acc[2][4] = {};

  auto STAGE = [&](int buf, int k0){
    #pragma unroll
    for (int c=0;c<4;c++){
      int id = c*512 + tid;
      int r = (id & 1023) >> 3;
      int kc = id & 7;
      int cs = (kc ^ (r & 7)) << 3;
      if (id < 1024)
        gload_lds16(A + (size_t)(bm+r)*K + k0 + cs, lsA[buf] + ((id & 1023) << 4));
      else
        gload_lds16(Bt + (size_t)(bn+r)*K + k0 + cs, lsB[buf] + ((id & 1023) << 4));
    }
  };

  STAGE(0, 0);
  int cur = 0;
  for (int k0 = 0; k0 < K; k0 += 64){
    __syncthreads();
    if (k0 + 64 < K) STAGE(cur^1, k0 + 64);
    #pragma unroll
    for (int ks=0;ks<2;ks++){
      bf16x8 af[2], bfr[4];
      #pragma unroll
      for (int i=0;i<2;i++){
        int ar = wm + i*16 + lrow;
        af[i] = *reinterpret_cast<const bf16x8*>(lsA[cur] + ((ar*128 + ks*64 + lgrp*16) ^ ((ar&7)<<4)));
      }
      #pragma unroll
      for (int j=0;j<4;j++){
        int br = wn + j*16 + lrow;
        bfr[j] = *reinterpret_cast<const bf16x8*>(lsB[cur] + ((br*128 + ks*64 + lgrp*16) ^ ((br&7)<<4)));
      }
      __builtin_amdgcn_s_setprio(1);
      #pragma unroll
      for (int i=0;i<2;i++)
        #pragma unroll
        for (int j=0;j<4;j++)
          acc[i][j] = __builtin_amdgcn_mfma_f32_16x16x32_bf16(af[i], bfr[j], acc[i][j], 0,0,0);
      __builtin_amdgcn_s_setprio(0);
    }
    cur ^= 1;
  }

  #pragma unroll
  for (int j=0;j<4;j++){
    int n = bn + wn + j*16 + lrow;
    float bv = bias[n];
    #pragma unroll
    for (int i=0;i<2;i++){
      int m0 = bm + wm + i*16 + lgrp*4;
      #pragma unroll
      for (int r=0;r<4;r++) dst[(size_t)(m0+r)*N + n] = acc[i][j][r] + bv;
    }
  }
}

// ------- causal flash attention: 8-wave QBLK=256 blocks, KV in 4 quarters -------
// qb (pre-scaled by 0.125*log2e), kb: [H][S][64] ; vtb: [H][64][S] (bf16)
// partials: pO bf16 [4][H][16 dquad][S][4], pml float2 [4][H][S]
__global__ __launch_bounds__(512, 2) void flash_attn_kernel(const u16* __restrict__ qb,
                                                            const u16* __restrict__ kb,
                                                            const u16* __restrict__ vtb,
                                                            u16* __restrict__ pO,
                                                            float2* __restrict__ pml){
  int b = blockIdx.x;
  int h = b & 15;                        // XCD = h&7 -> per-XCD L2 locality
  int u = b >> 4;                        // 0..63
  int qt = 15 - (u >> 2);                // heavy q-tiles dispatched first
  int quarter = u & 3;
  int seg = qt + 1;                      // KV tiles per quarter (nt = 4*(qt+1))
  int j0 = quarter * seg, j1 = j0 + seg;

  int tid = threadIdx.x, wave = tid >> 6, lane = tid & 63;
  int l31 = lane & 31, hi = lane >> 5;
  const u16* qh  = qb  + (size_t)h * S_LEN * 64;
  const u16* kh  = kb  + (size_t)h * S_LEN * 64;
  const u16* vth = vtb + (size_t)h * 64 * S_LEN;

  __shared__ __align__(16) unsigned char lsK[2][8192];
  __shared__ __align__(16) unsigned char lsV[2][8192];
  __shared__ __align__(16) u16 lsP[8][1024];   // per-wave P half-tile (32q x 32kv)
  unsigned char* Pw = (unsigned char*)lsP[wave];

  int qw = qt*256 + wave*32;             // lane's q-row = qw + l31

  bf16x8 qf[4];
  #pragma unroll
  for (int ks=0;ks<4;ks++)
    qf[ks] = *reinterpret_cast<const bf16x8*>(qh + (size_t)(qw + l31)*64 + ks*16 + hi*8);

  f32x16 oacc0 = {}, oacc1 = {};         // O^T rows d = df*32+(reg&3)+8*(reg>>2)+4hi, col q=l31
  float m_run = -3e38f, l_run = 0.f;

  auto STAGE = [&](int buf, int jj){
    int kv0 = jj*64;
    #pragma unroll
    for (int c=0;c<2;c++){
      int id = c*512 + tid;              // 0..1023 ; c=0 -> K, c=1 -> V (uniform per c)
      int r = (id >> 3) & 63;
      int kc = id & 7;
      int cs = (kc ^ (r & 7)) << 3;
      if (id < 512)
        gload_lds16(kh + (size_t)(kv0+r)*64 + cs, lsK[buf] + ((id & 511) << 4));
      else
        gload_lds16(vth + (size_t)r*S_LEN + kv0 + cs, lsV[buf] + ((id & 511) << 4));
    }
  };

  STAGE(0, j0);
  int cur = 0;
  for (int j = j0; j < j1; j++){
    __syncthreads();                     // all-thread barrier (no divergence around it)
    if (j + 1 < j1) STAGE(cur^1, j + 1);

    int kv0 = j*64;
    int rel0 = qw - kv0;                 // multiples of 32
    int rel1 = rel0 - 32;
    if (rel0 >= 0){                      // wave-uniform: any unmasked work this tile?
      bool act1 = rel1 >= 0;

      // ---- QK^T (swapped): S^T[kv][q] = K . Q^T ----
      f32x16 s0 = {}, s1 = {};
      __builtin_amdgcn_s_setprio(1);
      #pragma unroll
      for (int ks=0;ks<4;ks++){
        int row = l31;
        bf16x8 kf = *reinterpret_cast<const bf16x8*>(
            lsK[cur] + (row*128 + ((ks*32 + hi*16) ^ ((row&7)<<4))));
        s0 = __builtin_amdgcn_mfma_f32_32x32x16_bf16(kf, qf[ks], s0, 0,0,0);
      }
      if (act1){
        #pragma unroll
        for (int ks=0;ks<4;ks++){
          int row = 32 + l31;
          bf16x8 kf = *reinterpret_cast<const bf16x8*>(
              lsK[cur] + (row*128 + ((ks*32 + hi*16) ^ ((row&7)<<4))));
          s1 = __builtin_amdgcn_mfma_f32_32x32x16_bf16(kf, qf[ks], s1, 0,0,0);
        }
      }
      __builtin_amdgcn_s_setprio(0);

      // ---- causal mask on diagonal frags ----
      if (rel0 == 0){
        #pragma unroll
        for (int reg=0;reg<16;reg++){
          int kvloc = (reg & 3) + 8*(reg >> 2) + 4*hi;
          if (kvloc > l31) s0[reg] = -3e38f;
        }
      }
      if (act1 && rel1 == 0){
        #pragma unroll
        for (int reg=0;reg<16;reg++){
          int kvloc = (reg & 3) + 8*(reg >> 2) + 4*hi;
          if (kvloc > l31) s1[reg] = -3e38f;
        }
      }

      // ---- in-register online softmax (exp2 domain; Q pre-scaled) ----
      float mx = -3e38f;
      #pragma unroll
      for (int reg=0;reg<16;reg++) mx = fmaxf(mx, s0[reg]);
      if (act1){
        #pragma unroll
        for (int reg=0;reg<16;reg++) mx = fmaxf(mx, s1[reg]);
      }
      mx = fmaxf(mx, __shfl_xor(mx, 32));

      if (!__all(mx <= m_run + 11.54f)){ // defer-max (T13)
        float mnew = fmaxf(m_run, mx);
        float al = __builtin_amdgcn_exp2f(m_run - mnew);
        m_run = mnew; l_run *= al;
        #pragma unroll
        for (int reg=0;reg<16;reg++){ oacc0[reg] *= al; oacc1[reg] *= al; }
      }

      float ps = 0.f;
      #pragma unroll
      for (int reg=0;reg<16;reg++){
        float e = __builtin_amdgcn_exp2f(s0[reg] - m_run);
        s0[reg] = e; ps += e;
      }
      if (act1){
        #pragma unroll
        for (int reg=0;reg<16;reg++){
          float e = __builtin_amdgcn_exp2f(s1[reg] - m_run);
          s1[reg] = e; ps += e;
        }
      }
      ps += __shfl_xor(ps, 32);
      l_run += ps;

      // ---- f=0: P half-tile bounce + PV (ks = 0,1) ----
      #pragma unroll
      for (int m=0;m<4;m++){
        u32 w0p, w1p;
        asm("v_cvt_pk_bf16_f32 %0, %1, %2" : "=v"(w0p) : "v"(s0[4*m+0]), "v"(s0[4*m+1]));
        asm("v_cvt_pk_bf16_f32 %0, %1, %2" : "=v"(w1p) : "v"(s0[4*m+2]), "v"(s0[4*m+3]));
        int off = l31*64 + ((m ^ (l31 & 3)) << 4) + hi*8;
        uint2 pv; pv.x = w0p; pv.y = w1p;
        *reinterpret_cast<uint2*>(Pw + off) = pv;
      }
      __builtin_amdgcn_s_setprio(1);
      #pragma unroll
      for (int ksl=0;ksl<2;ksl++){
        bf16x8 pb = *reinterpret_cast<const bf16x8*>(
            Pw + l31*64 + (((2*ksl + hi) ^ (l31 & 3)) << 4));
        int row0 = l31;
        bf16x8 vf0 = *reinterpret_cast<const bf16x8*>(
            lsV[cur] + (row0*128 + ((ksl*32 + hi*16) ^ ((row0&7)<<4))));
        oacc0 = __builtin_amdgcn_mfma_f32_32x32x16_bf16(vf0, pb, oacc0, 0,0,0);
        int row1 = 32 + l31;
        bf16x8 vf1 = *reinterpret_cast<const bf16x8*>(
            lsV[cur] + (row1*128 + ((ksl*32 + hi*16) ^ ((row1&7)<<4))));
        oacc1 = __builtin_amdgcn_mfma_f32_32x32x16_bf16(vf1, pb, oacc1, 0,0,0);
      }
      __builtin_amdgcn_s_setprio(0);

      // ---- f=1: same with s1 (ks = 2,3) ----
      if (act1){
        #pragma unroll
        for (int m=0;m<4;m++){
          u32 w0p, w1p;
          asm("v_cvt_pk_bf16_f32 %0, %1, %2" : "=v"(w0p) : "v"(s1[4*m+0]), "v"(s1[4*m+1]));
          asm("v_cvt_pk_bf16_f32 %0, %1, %2" : "=v"(w1p) : "v"(s1[4*m+2]), "v"(s1[4*m+3]));
          int off = l31*64 + ((m ^ (l31 & 3)) << 4) + hi*8;
          uint2 pv; pv.x = w0p; pv.y = w1p;
          *reinterpret_cast<uint2*>(Pw + off) = pv;
        }
        __builtin_amdgcn_s_setprio(1);
        #pragma unroll
        for (int ksl=0;ksl<2;ksl++){
          int ks = 2 + ksl;
          bf16x8 pb = *reinterpret_cast<const bf16x8*>(
              Pw + l31*64 + (((2*ksl + hi) ^ (l31 & 3)) << 4));
          int row0 = l31;
          bf16x8 vf0 = *reinterpret_cast<const bf16x8*>(
              lsV[cur] + (row0*128 + ((ks*32 + hi*16) ^ ((row0&7)<<4))));
          oacc0 = __builtin_amdgcn_mfma_f32_32x32x16_bf16(vf0, pb, oacc0, 0,0,0);
          int row1 = 32 + l31;
          bf16x8 vf1 = *reinterpret_cast<const bf16x8*>(
              lsV[cur] + (row1*128 + ((ks*32 + hi*16) ^ ((row1&7)<<4))));
          oacc1 = __builtin_amdgcn_mfma_f32_32x32x16_bf16(vf1, pb, oacc1, 0,0,0);
        }
        __builtin_amdgcn_s_setprio(0);
      }
    }
    cur ^= 1;
  }

  // ---- epilogue: write partial (m, l, unnormalized O as bf16) ----
  int q = qw + l31;
  if (hi == 0){
    float2 ml; ml.x = m_run; ml.y = l_run;
    pml[((size_t)quarter*NH + h)*S_LEN + q] = ml;
  }
  #pragma unroll
  for (int df=0;df<2;df++){
    #pragma unroll
    for (int q4=0;q4<4;q4++){
      float a0 = df ? oacc1[4*q4+0] : oacc0[4*q4+0];
      float a1 = df ? oacc1[4*q4+1] : oacc0[4*q4+1];
      float a2 = df ? oacc1[4*q4+2] : oacc0[4*q4+2];
      float a3 = df ? oacc1[4*q4+3] : oacc0[4*q4+3];
      u32 w0d, w1d;
      asm("v_cvt_pk_bf16_f32 %0, %1, %2" : "=v"(w0d) : "v"(a0), "v"(a1));
      asm("v_cvt_pk_bf16_f32 %0, %1, %2" : "=v"(w1d) : "v"(a2), "v"(a3));
      int dquad = df*8 + 2*q4 + hi;      // d/4 for d = df*32 + 8*q4 + 4*hi
      uint2 pv; pv.x = w0d; pv.y = w1d;
      *reinterpret_cast<uint2*>(pO + (((size_t)(quarter*NH + h)*16 + dquad)*S_LEN + q)*4) = pv;
    }
  }
}

// ------- combine four KV-quarter partials -> catb bf16 [S][1024] -------
__global__ __launch_bounds__(256) void combine_kernel(const u16* __restrict__ pO,
                                                      const float2* __restrict__ pml,
                                                      u16* __restrict__ catb){
  int tid = threadIdx.x;
  int dq = tid & 15, qo = tid >> 4;
  int h = blockIdx.y;
  int q = blockIdx.x*16 + qo;
  float2 ml[4];
  #pragma unroll
  for (int i=0;i<4;i++) ml[i] = pml[((size_t)i*NH + h)*S_LEN + q];
  float m = fmaxf(fmaxf(ml[0].x, ml[1].x), fmaxf(ml[2].x, ml[3].x));
  float w[4], denom = 0.f;
  #pragma unroll
  for (int i=0;i<4;i++){ w[i] = __builtin_amdgcn_exp2f(ml[i].x - m); denom += w[i]*ml[i].y; }
  float inv = 1.0f / denom;
  float x0=0.f, x1=0.f, x2=0.f, x3=0.f;
  #pragma unroll
  for (int i=0;i<4;i++){
    ushort4 a = reinterpret_cast<const ushort4*>(pO)[((size_t)i*NH*16 + (size_t)h*16 + dq)*S_LEN + q];
    x0 += __uint_as_float((u32)a.x << 16) * w[i];
    x1 += __uint_as_float((u32)a.y << 16) * w[i];
    x2 += __uint_as_float((u32)a.z << 16) * w[i];
    x3 += __uint_as_float((u32)a.w << 16) * w[i];
  }
  ushort4 o;
  o.x = f2bf(x0*inv); o.y = f2bf(x1*inv); o.z = f2bf(x2*inv); o.w = f2bf(x3*inv);
  *reinterpret_cast<ushort4*>(catb + (size_t)q*D_MODEL + h*64 + dq*4) = o;
}

extern "C" void kernel_launch(void* const* d_in, const int* in_sizes, int n_in,
                              void* d_out, int out_size, void* d_ws, size_t ws_size,
                              hipStream_t stream){
  (void)in_sizes; (void)n_in; (void)out_size; (void)ws_size;
  const float* V  = (const float*)d_in[0];
  const float* Km = (const float*)d_in[1];
  const float* Q  = (const float*)d_in[2];
  const float* WQ = (const float*)d_in[3];
  const float* bQ = (const float*)d_in[4];
  const float* WK = (const float*)d_in[5];
  const float* bK = (const float*)d_in[6];
  const float* WV = (const float*)d_in[7];
  const float* bV = (const float*)d_in[8];
  const float* WO = (const float*)d_in[9];
  const float* bO = (const float*)d_in[10];
  float* out = (float*)d_out;

  char* ws = (char*)d_ws;
  const size_t SZ_SD = (size_t)S_LEN * D_MODEL * 2;    // 8 MiB
  const size_t SZ_W  = (size_t)D_MODEL * D_MODEL * 2;  // 2 MiB
  u16* Qb   = (u16*)(ws);
  u16* Kb   = (u16*)(ws + SZ_SD);
  u16* Vb   = (u16*)(ws + 2*SZ_SD);
  u16* WtQ  = (u16*)(ws + 3*SZ_SD);
  u16* WtK  = (u16*)(ws + 3*SZ_SD + SZ_W);
  u16* WtV  = (u16*)(ws + 3*SZ_SD + 2*SZ_W);
  u16* WtO  = (u16*)(ws + 3*SZ_SD + 3*SZ_W);
  u16* qbuf = (u16*)(ws + 3*SZ_SD + 4*SZ_W);
  u16* kbuf = (u16*)(ws + 4*SZ_SD + 4*SZ_W);
  u16* vtb  = (u16*)(ws + 5*SZ_SD + 4*SZ_W);
  u16* catb = (u16*)(ws + 6*SZ_SD + 4*SZ_W);
  u16* pO   = (u16*)(ws + 7*SZ_SD + 4*SZ_W);           // 32 MiB: [4][16][16][4096][4] u16
  float2* pml = (float2*)(ws + 11*SZ_SD + 4*SZ_W);     // 2 MiB: [4][16][4096] float2
  // total: ~98 MiB

  const float QSCALE = 0.18033688011112042f;   // 0.125 * log2(e)

  cvt3_kernel<<<dim3(4096,3),256,0,stream>>>(Q, Km, V, Qb, Kb, Vb);
  tcvt_qkv_kernel<<<dim3(16,3,16),256,0,stream>>>(WQ, WK, WV, WtQ, WtK, WtV);
  tcvt_wo_kernel<<<dim3(16,16),256,0,stream>>>(WO, WtO);
  gemm_qkv_kernel<<<dim3(8,32,3),512,0,stream>>>(Qb, Kb, Vb, WtQ, WtK, WtV,
                                                 bQ, bK, bV, qbuf, kbuf, vtb, QSCALE);
  flash_attn_kernel<<<dim3(1024),512,0,stream>>>(qbuf, kbuf, vtb, pO, pml);
  combine_kernel<<<dim3(256,16),256,0,stream>>>(pO, pml, catb);
  gemm_out_kernel<<<dim3(8,32),512,0,stream>>>(catb, WtO, bO, out, S_LEN, D_MODEL, D_MODEL);
}

// Round 8
// 155.992 us; speedup vs baseline: 2.3911x; 1.0400x over previous
//
#include <hip/hip_runtime.h>

typedef unsigned short u16;
typedef unsigned int u32;
typedef __attribute__((ext_vector_type(8))) __bf16 bf16x8;
typedef __attribute__((ext_vector_type(4))) float f32x4;
typedef __attribute__((ext_vector_type(16))) float f32x16;

#define S_LEN 4096
#define D_MODEL 1024
#define NH 16
#define DHEAD 64

__device__ __forceinline__ u16 f2bf(float f){
  unsigned u = __float_as_uint(f);
  u += 0x7FFFu + ((u >> 16) & 1u);   // RTNE
  return (u16)(u >> 16);
}

__device__ __forceinline__ void gload_lds16(const void* g, void* l){
  __builtin_amdgcn_global_load_lds((const __attribute__((address_space(1))) void*)g,
                                   (__attribute__((address_space(3))) void*)l, 16, 0, 0);
}

// ---------------- fp32 -> bf16, three tensors in one launch ----------------
__global__ __launch_bounds__(256) void cvt3_kernel(const float* __restrict__ q,
                                                   const float* __restrict__ k,
                                                   const float* __restrict__ v,
                                                   u16* __restrict__ oq,
                                                   u16* __restrict__ ok,
                                                   u16* __restrict__ ov){
  int z = blockIdx.y;
  const float* in = (z==0)? q : (z==1)? k : v;
  u16* out = (z==0)? oq : (z==1)? ok : ov;
  int i = blockIdx.x*256 + threadIdx.x;
  float4 w = reinterpret_cast<const float4*>(in)[i];
  ushort4 o;
  o.x = f2bf(w.x); o.y = f2bf(w.y); o.z = f2bf(w.z); o.w = f2bf(w.w);
  reinterpret_cast<ushort4*>(out)[i] = o;
}

// ------- transpose+convert QKV weights: [16][1024][64] fp32 -> [16][64][1024] bf16 -------
__global__ __launch_bounds__(256) void tcvt_qkv_kernel(const float* __restrict__ wq,
                                                       const float* __restrict__ wk,
                                                       const float* __restrict__ wv,
                                                       u16* __restrict__ oq,
                                                       u16* __restrict__ ok,
                                                       u16* __restrict__ ov){
  int which = blockIdx.y;
  const float* in = (which==0)? wq : (which==1)? wk : wv;
  u16* out = (which==0)? oq : (which==1)? ok : ov;
  __shared__ float tile[64][67];
  int z = blockIdx.z;
  const float* inh = in + (size_t)z*1024*64;
  u16* outh = out + (size_t)z*1024*64;
  int tid = threadIdx.x;
  int r0 = blockIdx.x*64;
  #pragma unroll
  for (int c=0;c<4;c++){
    int cl = c*256 + tid;
    int row = cl >> 4, cc = (cl & 15) * 4;
    float4 v = *reinterpret_cast<const float4*>(inh + (size_t)(r0+row)*64 + cc);
    tile[row][cc+0]=v.x; tile[row][cc+1]=v.y; tile[row][cc+2]=v.z; tile[row][cc+3]=v.w;
  }
  __syncthreads();
  #pragma unroll
  for (int c=0;c<4;c++){
    int cl = c*256 + tid;
    int crow = cl >> 4, rc = (cl & 15) * 4;
    ushort4 o;
    o.x = f2bf(tile[rc+0][crow]);
    o.y = f2bf(tile[rc+1][crow]);
    o.z = f2bf(tile[rc+2][crow]);
    o.w = f2bf(tile[rc+3][crow]);
    *reinterpret_cast<ushort4*>(outh + (size_t)crow*1024 + r0 + rc) = o;
  }
}

// ------- transpose+convert WO: [1024][1024] fp32 -> WO^T bf16 -------
__global__ __launch_bounds__(256) void tcvt_wo_kernel(const float* __restrict__ in,
                                                      u16* __restrict__ out){
  __shared__ float tile[64][67];
  int r0 = blockIdx.x*64, c0 = blockIdx.y*64;
  int tid = threadIdx.x;
  #pragma unroll
  for (int c=0;c<4;c++){
    int cl = c*256 + tid;
    int row = cl >> 4, cc = (cl & 15) * 4;
    float4 v = *reinterpret_cast<const float4*>(in + (size_t)(r0+row)*1024 + c0 + cc);
    tile[row][cc+0]=v.x; tile[row][cc+1]=v.y; tile[row][cc+2]=v.z; tile[row][cc+3]=v.w;
  }
  __syncthreads();
  #pragma unroll
  for (int c=0;c<4;c++){
    int cl = c*256 + tid;
    int crow = cl >> 4, rc = (cl & 15) * 4;
    ushort4 o;
    o.x = f2bf(tile[rc+0][crow]);
    o.y = f2bf(tile[rc+1][crow]);
    o.z = f2bf(tile[rc+2][crow]);
    o.w = f2bf(tile[rc+3][crow]);
    *reinterpret_cast<ushort4*>(out + (size_t)(c0+crow)*1024 + r0 + rc) = o;
  }
}

// ------- fused QKV projection GEMM: z selects {Q,K,V} ; 8 waves, 128x128 tile -------
// z=0,1: bf16 -> [H][S][64] ; z=2: bf16 -> [H][64][S] (V^T)
__global__ __launch_bounds__(512) void gemm_qkv_kernel(
    const u16* __restrict__ Qb, const u16* __restrict__ Kb, const u16* __restrict__ Vb,
    const u16* __restrict__ WtQ, const u16* __restrict__ WtK, const u16* __restrict__ WtV,
    const float* __restrict__ bQ, const float* __restrict__ bK, const float* __restrict__ bV,
    u16* __restrict__ qbuf, u16* __restrict__ kbuf, u16* __restrict__ vtb, float qscale){
  const int M = S_LEN, N = D_MODEL, K = D_MODEL;
  int z = blockIdx.z;
  const u16* A  = (z==0)? Qb  : (z==1)? Kb  : Vb;
  const u16* Bt = (z==0)? WtQ : (z==1)? WtK : WtV;
  const float* bias = (z==0)? bQ : (z==1)? bK : bV;
  float oscale = (z==0)? qscale : 1.0f;

  __shared__ __align__(16) unsigned char lsA[2][16384];
  __shared__ __align__(16) unsigned char lsB[2][16384];
  int tid = threadIdx.x;
  int bm = blockIdx.y * 128, bn = blockIdx.x * 128;
  int wave = tid >> 6, lane = tid & 63;
  int wm = (wave >> 1) * 32, wn = (wave & 1) * 64;
  int lrow = lane & 15, lgrp = lane >> 4;

  f32x4 acc[2][4] = {};

  auto STAGE = [&](int buf, int k0){
    #pragma unroll
    for (int c=0;c<4;c++){
      int id = c*512 + tid;
      int r = (id & 1023) >> 3;
      int kc = id & 7;
      int cs = (kc ^ (r & 7)) << 3;
      if (id < 1024)
        gload_lds16(A + (size_t)(bm+r)*K + k0 + cs, lsA[buf] + ((id & 1023) << 4));
      else
        gload_lds16(Bt + (size_t)(bn+r)*K + k0 + cs, lsB[buf] + ((id & 1023) << 4));
    }
  };

  STAGE(0, 0);
  int cur = 0;
  for (int k0 = 0; k0 < K; k0 += 64){
    __syncthreads();
    if (k0 + 64 < K) STAGE(cur^1, k0 + 64);
    #pragma unroll
    for (int ks=0;ks<2;ks++){
      bf16x8 af[2], bfr[4];
      #pragma unroll
      for (int i=0;i<2;i++){
        int ar = wm + i*16 + lrow;
        af[i] = *reinterpret_cast<const bf16x8*>(lsA[cur] + ((ar*128 + ks*64 + lgrp*16) ^ ((ar&7)<<4)));
      }
      #pragma unroll
      for (int j=0;j<4;j++){
        int br = wn + j*16 + lrow;
        bfr[j] = *reinterpret_cast<const bf16x8*>(lsB[cur] + ((br*128 + ks*64 + lgrp*16) ^ ((br&7)<<4)));
      }
      __builtin_amdgcn_s_setprio(1);
      #pragma unroll
      for (int i=0;i<2;i++)
        #pragma unroll
        for (int j=0;j<4;j++)
          acc[i][j] = __builtin_amdgcn_mfma_f32_16x16x32_bf16(af[i], bfr[j], acc[i][j], 0,0,0);
      __builtin_amdgcn_s_setprio(0);
    }
    cur ^= 1;
  }

  #pragma unroll
  for (int j=0;j<4;j++){
    int n = bn + wn + j*16 + lrow;
    float bv = bias[n];
    int hh = n >> 6, kk = n & 63;
    #pragma unroll
    for (int i=0;i<2;i++){
      int m0 = bm + wm + i*16 + lgrp*4;
      float v[4];
      #pragma unroll
      for (int r=0;r<4;r++) v[r] = (acc[i][j][r] + bv) * oscale;
      if (z < 2){
        u16* o = (z==0)? qbuf : kbuf;
        #pragma unroll
        for (int r=0;r<4;r++) o[((size_t)hh*M + m0 + r)*64 + kk] = f2bf(v[r]);
      } else {
        ushort4 p; p.x=f2bf(v[0]); p.y=f2bf(v[1]); p.z=f2bf(v[2]); p.w=f2bf(v[3]);
        *reinterpret_cast<ushort4*>(vtb + ((size_t)hh*64 + kk)*M + m0) = p;
      }
    }
  }
}

// ------- output GEMM: fp32 [M][N] -------
__global__ __launch_bounds__(512) void gemm_out_kernel(const u16* __restrict__ A,
                                                       const u16* __restrict__ Bt,
                                                       const float* __restrict__ bias,
                                                       float* __restrict__ dst,
                                                       int M, int N, int K){
  __shared__ __align__(16) unsigned char lsA[2][16384];
  __shared__ __align__(16) unsigned char lsB[2][16384];
  int tid = threadIdx.x;
  int bm = blockIdx.y * 128, bn = blockIdx.x * 128;
  int wave = tid >> 6, lane = tid & 63;
  int wm = (wave >> 1) * 32, wn = (wave & 1) * 64;
  int lrow = lane & 15, lgrp = lane >> 4;

  f32x4 acc[2][4] = {};

  auto STAGE = [&](int buf, int k0){
    #pragma unroll
    for (int c=0;c<4;c++){
      int id = c*512 + tid;
      int r = (id & 1023) >> 3;
      int kc = id & 7;
      int cs = (kc ^ (r & 7)) << 3;
      if (id < 1024)
        gload_lds16(A + (size_t)(bm+r)*K + k0 + cs, lsA[buf] + ((id & 1023) << 4));
      else
        gload_lds16(Bt + (size_t)(bn+r)*K + k0 + cs, lsB[buf] + ((id & 1023) << 4));
    }
  };

  STAGE(0, 0);
  int cur = 0;
  for (int k0 = 0; k0 < K; k0 += 64){
    __syncthreads();
    if (k0 + 64 < K) STAGE(cur^1, k0 + 64);
    #pragma unroll
    for (int ks=0;ks<2;ks++){
      bf16x8 af[2], bfr[4];
      #pragma unroll
      for (int i=0;i<2;i++){
        int ar = wm + i*16 + lrow;
        af[i] = *reinterpret_cast<const bf16x8*>(lsA[cur] + ((ar*128 + ks*64 + lgrp*16) ^ ((ar&7)<<4)));
      }
      #pragma unroll
      for (int j=0;j<4;j++){
        int br = wn + j*16 + lrow;
        bfr[j] = *reinterpret_cast<const bf16x8*>(lsB[cur] + ((br*128 + ks*64 + lgrp*16) ^ ((br&7)<<4)));
      }
      __builtin_amdgcn_s_setprio(1);
      #pragma unroll
      for (int i=0;i<2;i++)
        #pragma unroll
        for (int j=0;j<4;j++)
          acc[i][j] = __builtin_amdgcn_mfma_f32_16x16x32_bf16(af[i], bfr[j], acc[i][j], 0,0,0);
      __builtin_amdgcn_s_setprio(0);
    }
    cur ^= 1;
  }

  #pragma unroll
  for (int j=0;j<4;j++){
    int n = bn + wn + j*16 + lrow;
    float bv = bias[n];
    #pragma unroll
    for (int i=0;i<2;i++){
      int m0 = bm + wm + i*16 + lgrp*4;
      #pragma unroll
      for (int r=0;r<4;r++) dst[(size_t)(m0+r)*N + n] = acc[i][j][r] + bv;
    }
  }
}

// ------- causal flash attention: 8-wave QBLK=256, KV quarters, k-major LDS -------
// LDS layouts (conflict-free, linear per instruction):
//   K : [8 c][64 row][16B]  unit = c*64+row  holds K[kv0+row][c*8 .. +8)
//   V : [8 c][64 d  ][16B]  unit = c*64+d    holds V^T[d][kv0+c*8 .. +8)
//   P : per-wave [4 kvblock][32 q][16B]      kv-major packed bf16
__global__ __launch_bounds__(512, 2) void flash_attn_kernel(const u16* __restrict__ qb,
                                                            const u16* __restrict__ kb,
                                                            const u16* __restrict__ vtb,
                                                            u16* __restrict__ pO,
                                                            float2* __restrict__ pml){
  int b = blockIdx.x;
  int h = b & 15;                        // XCD = h&7 -> per-XCD L2 locality
  int u = b >> 4;                        // 0..63
  int qt = 15 - (u >> 2);                // heavy q-tiles dispatched first
  int quarter = u & 3;
  int seg = qt + 1;                      // KV tiles per quarter
  int j0 = quarter * seg, j1 = j0 + seg;

  int tid = threadIdx.x, wave = tid >> 6, lane = tid & 63;
  int l31 = lane & 31, hi = lane >> 5;
  const u16* qh  = qb  + (size_t)h * S_LEN * 64;
  const u16* kh  = kb  + (size_t)h * S_LEN * 64;
  const u16* vth = vtb + (size_t)h * 64 * S_LEN;

  __shared__ __align__(16) unsigned char lsK[2][16384];
  __shared__ __align__(16) unsigned char lsV[2][16384];
  __shared__ __align__(16) unsigned char lsP[8][2048];
  unsigned char* Pw = lsP[wave];

  int qw = qt*256 + wave*32;             // lane's q-row = qw + l31

  bf16x8 qf[4];
  #pragma unroll
  for (int ks=0;ks<4;ks++)
    qf[ks] = *reinterpret_cast<const bf16x8*>(qh + (size_t)(qw + l31)*64 + ks*16 + hi*8);

  f32x16 oacc0 = {}, oacc1 = {};         // O^T rows d = df*32+(reg&3)+8*(reg>>2)+4hi, col q=l31
  float m_run = -3e38f, l_run = 0.f;

  // per-thread LDS read bases (all reads become base + compile-time offset)
  const int kvbase = hi*1024 + l31*16;   // K/V frag base
  const int prbase = hi*512  + l31*16;   // P read base
  const int pwbase = l31*16  + hi*8;     // P write base

  // staging source offsets (elements)
  const int krow = tid & 63, kcol = (tid >> 6) << 3;

  auto STAGE = [&](int buf, int jj){
    int kv0 = jj*64;
    gload_lds16(kh + (size_t)(kv0 + krow)*64 + kcol, lsK[buf] + (tid << 4));
    gload_lds16(vth + (size_t)krow*S_LEN + kv0 + kcol, lsV[buf] + (tid << 4));
  };

  STAGE(0, j0);
  int cur = 0;
  for (int j = j0; j < j1; j++){
    __syncthreads();                     // all-thread barrier (no divergence around it)
    if (j + 1 < j1) STAGE(cur^1, j + 1);

    int kv0 = j*64;
    int rel0 = qw - kv0;                 // multiples of 32
    int rel1 = rel0 - 32;
    if (rel0 >= 0){                      // wave-uniform: any unmasked work this tile?
      bool act1 = rel1 >= 0;
      const unsigned char* Kc = lsK[cur] + kvbase;
      const unsigned char* Vc = lsV[cur] + kvbase;

      // ---- QK^T (swapped): S^T[kv][q] = K . Q^T ----
      f32x16 s0 = {}, s1 = {};
      __builtin_amdgcn_s_setprio(1);
      #pragma unroll
      for (int ks=0;ks<4;ks++){
        bf16x8 kf = *reinterpret_cast<const bf16x8*>(Kc + ks*2048);
        s0 = __builtin_amdgcn_mfma_f32_32x32x16_bf16(kf, qf[ks], s0, 0,0,0);
      }
      if (act1){
        #pragma unroll
        for (int ks=0;ks<4;ks++){
          bf16x8 kf = *reinterpret_cast<const bf16x8*>(Kc + ks*2048 + 512);
          s1 = __builtin_amdgcn_mfma_f32_32x32x16_bf16(kf, qf[ks], s1, 0,0,0);
        }
      }
      __builtin_amdgcn_s_setprio(0);

      // ---- causal mask on diagonal frags ----
      if (rel0 == 0){
        #pragma unroll
        for (int reg=0;reg<16;reg++){
          int kvloc = (reg & 3) + 8*(reg >> 2) + 4*hi;
          if (kvloc > l31) s0[reg] = -3e38f;
        }
      }
      if (act1 && rel1 == 0){
        #pragma unroll
        for (int reg=0;reg<16;reg++){
          int kvloc = (reg & 3) + 8*(reg >> 2) + 4*hi;
          if (kvloc > l31) s1[reg] = -3e38f;
        }
      }

      // ---- in-register online softmax (exp2 domain; Q pre-scaled) ----
      float mx = -3e38f;
      #pragma unroll
      for (int reg=0;reg<16;reg++) mx = fmaxf(mx, s0[reg]);
      if (act1){
        #pragma unroll
        for (int reg=0;reg<16;reg++) mx = fmaxf(mx, s1[reg]);
      }
      mx = fmaxf(mx, __shfl_xor(mx, 32));

      if (!__all(mx <= m_run + 11.54f)){ // defer-max (T13)
        float mnew = fmaxf(m_run, mx);
        float al = __builtin_amdgcn_exp2f(m_run - mnew);
        m_run = mnew; l_run *= al;
        #pragma unroll
        for (int reg=0;reg<16;reg++){ oacc0[reg] *= al; oacc1[reg] *= al; }
      }

      float ps = 0.f;
      #pragma unroll
      for (int reg=0;reg<16;reg++){
        float e = __builtin_amdgcn_exp2f(s0[reg] - m_run);
        s0[reg] = e; ps += e;
      }
      if (act1){
        #pragma unroll
        for (int reg=0;reg<16;reg++){
          float e = __builtin_amdgcn_exp2f(s1[reg] - m_run);
          s1[reg] = e; ps += e;
        }
      }
      ps += __shfl_xor(ps, 32);
      l_run += ps;

      // ---- f=0: pack P (kv-major) + PV (ks-global 0,1) ----
      // lane(q=l31,hi) reg r holds P^T[kv][q], kv = 4hi + (r&3) + 8(r>>2)
      // write b-th uint2 at b*512 + q*16 + hi*8 = unit(b,q) words {2hi,2hi+1}
      #pragma unroll
      for (int bb=0;bb<4;bb++){
        u32 w0p, w1p;
        asm("v_cvt_pk_bf16_f32 %0, %1, %2" : "=v"(w0p) : "v"(s0[4*bb+0]), "v"(s0[4*bb+1]));
        asm("v_cvt_pk_bf16_f32 %0, %1, %2" : "=v"(w1p) : "v"(s0[4*bb+2]), "v"(s0[4*bb+3]));
        uint2 pv; pv.x = w0p; pv.y = w1p;
        *reinterpret_cast<uint2*>(Pw + bb*512 + pwbase) = pv;
      }
      __builtin_amdgcn_s_setprio(1);
      #pragma unroll
      for (int ksl=0;ksl<2;ksl++){
        bf16x8 pb = *reinterpret_cast<const bf16x8*>(Pw + prbase + ksl*1024);
        bf16x8 vf0 = *reinterpret_cast<const bf16x8*>(Vc + ksl*2048);
        bf16x8 vf1 = *reinterpret_cast<const bf16x8*>(Vc + ksl*2048 + 512);
        oacc0 = __builtin_amdgcn_mfma_f32_32x32x16_bf16(vf0, pb, oacc0, 0,0,0);
        oacc1 = __builtin_amdgcn_mfma_f32_32x32x16_bf16(vf1, pb, oacc1, 0,0,0);
      }
      __builtin_amdgcn_s_setprio(0);

      // ---- f=1: same with s1 (ks-global 2,3) ----
      if (act1){
        #pragma unroll
        for (int bb=0;bb<4;bb++){
          u32 w0p, w1p;
          asm("v_cvt_pk_bf16_f32 %0, %1, %2" : "=v"(w0p) : "v"(s1[4*bb+0]), "v"(s1[4*bb+1]));
          asm("v_cvt_pk_bf16_f32 %0, %1, %2" : "=v"(w1p) : "v"(s1[4*bb+2]), "v"(s1[4*bb+3]));
          uint2 pv; pv.x = w0p; pv.y = w1p;
          *reinterpret_cast<uint2*>(Pw + bb*512 + pwbase) = pv;
        }
        __builtin_amdgcn_s_setprio(1);
        #pragma unroll
        for (int ksl=0;ksl<2;ksl++){
          bf16x8 pb = *reinterpret_cast<const bf16x8*>(Pw + prbase + ksl*1024);
          bf16x8 vf0 = *reinterpret_cast<const bf16x8*>(Vc + (2+ksl)*2048);
          bf16x8 vf1 = *reinterpret_cast<const bf16x8*>(Vc + (2+ksl)*2048 + 512);
          oacc0 = __builtin_amdgcn_mfma_f32_32x32x16_bf16(vf0, pb, oacc0, 0,0,0);
          oacc1 = __builtin_amdgcn_mfma_f32_32x32x16_bf16(vf1, pb, oacc1, 0,0,0);
        }
        __builtin_amdgcn_s_setprio(0);
      }
    }
    cur ^= 1;
  }

  // ---- epilogue: write partial (m, l, unnormalized O as bf16) ----
  int q = qw + l31;
  if (hi == 0){
    float2 ml; ml.x = m_run; ml.y = l_run;
    pml[((size_t)quarter*NH + h)*S_LEN + q] = ml;
  }
  #pragma unroll
  for (int df=0;df<2;df++){
    #pragma unroll
    for (int q4=0;q4<4;q4++){
      float a0 = df ? oacc1[4*q4+0] : oacc0[4*q4+0];
      float a1 = df ? oacc1[4*q4+1] : oacc0[4*q4+1];
      float a2 = df ? oacc1[4*q4+2] : oacc0[4*q4+2];
      float a3 = df ? oacc1[4*q4+3] : oacc0[4*q4+3];
      u32 w0d, w1d;
      asm("v_cvt_pk_bf16_f32 %0, %1, %2" : "=v"(w0d) : "v"(a0), "v"(a1));
      asm("v_cvt_pk_bf16_f32 %0, %1, %2" : "=v"(w1d) : "v"(a2), "v"(a3));
      int dquad = df*8 + 2*q4 + hi;      // d/4 for d = df*32 + 8*q4 + 4*hi
      uint2 pv; pv.x = w0d; pv.y = w1d;
      *reinterpret_cast<uint2*>(pO + (((size_t)(quarter*NH + h)*16 + dquad)*S_LEN + q)*4) = pv;
    }
  }
}

// ------- combine four KV-quarter partials -> catb bf16 [S][1024] -------
__global__ __launch_bounds__(256) void combine_kernel(const u16* __restrict__ pO,
                                                      const float2* __restrict__ pml,
                                                      u16* __restrict__ catb){
  int tid = threadIdx.x;
  int dq = tid & 15, qo = tid >> 4;
  int h = blockIdx.y;
  int q = blockIdx.x*16 + qo;
  float2 ml[4];
  #pragma unroll
  for (int i=0;i<4;i++) ml[i] = pml[((size_t)i*NH + h)*S_LEN + q];
  float m = fmaxf(fmaxf(ml[0].x, ml[1].x), fmaxf(ml[2].x, ml[3].x));
  float w[4], denom = 0.f;
  #pragma unroll
  for (int i=0;i<4;i++){ w[i] = __builtin_amdgcn_exp2f(ml[i].x - m); denom += w[i]*ml[i].y; }
  float inv = 1.0f / denom;
  float x0=0.f, x1=0.f, x2=0.f, x3=0.f;
  #pragma unroll
  for (int i=0;i<4;i++){
    ushort4 a = reinterpret_cast<const ushort4*>(pO)[((size_t)i*NH*16 + (size_t)h*16 + dq)*S_LEN + q];
    x0 += __uint_as_float((u32)a.x << 16) * w[i];
    x1 += __uint_as_float((u32)a.y << 16) * w[i];
    x2 += __uint_as_float((u32)a.z << 16) * w[i];
    x3 += __uint_as_float((u32)a.w << 16) * w[i];
  }
  ushort4 o;
  o.x = f2bf(x0*inv); o.y = f2bf(x1*inv); o.z = f2bf(x2*inv); o.w = f2bf(x3*inv);
  *reinterpret_cast<ushort4*>(catb + (size_t)q*D_MODEL + h*64 + dq*4) = o;
}

extern "C" void kernel_launch(void* const* d_in, const int* in_sizes, int n_in,
                              void* d_out, int out_size, void* d_ws, size_t ws_size,
                              hipStream_t stream){
  (void)in_sizes; (void)n_in; (void)out_size; (void)ws_size;
  const float* V  = (const float*)d_in[0];
  const float* Km = (const float*)d_in[1];
  const float* Q  = (const float*)d_in[2];
  const float* WQ = (const float*)d_in[3];
  const float* bQ = (const float*)d_in[4];
  const float* WK = (const float*)d_in[5];
  const float* bK = (const float*)d_in[6];
  const float* WV = (const float*)d_in[7];
  const float* bV = (const float*)d_in[8];
  const float* WO = (const float*)d_in[9];
  const float* bO = (const float*)d_in[10];
  float* out = (float*)d_out;

  char* ws = (char*)d_ws;
  const size_t SZ_SD = (size_t)S_LEN * D_MODEL * 2;    // 8 MiB
  const size_t SZ_W  = (size_t)D_MODEL * D_MODEL * 2;  // 2 MiB
  u16* Qb   = (u16*)(ws);
  u16* Kb   = (u16*)(ws + SZ_SD);
  u16* Vb   = (u16*)(ws + 2*SZ_SD);
  u16* WtQ  = (u16*)(ws + 3*SZ_SD);
  u16* WtK  = (u16*)(ws + 3*SZ_SD + SZ_W);
  u16* WtV  = (u16*)(ws + 3*SZ_SD + 2*SZ_W);
  u16* WtO  = (u16*)(ws + 3*SZ_SD + 3*SZ_W);
  u16* qbuf = (u16*)(ws + 3*SZ_SD + 4*SZ_W);
  u16* kbuf = (u16*)(ws + 4*SZ_SD + 4*SZ_W);
  u16* vtb  = (u16*)(ws + 5*SZ_SD + 4*SZ_W);
  u16* catb = (u16*)(ws + 6*SZ_SD + 4*SZ_W);
  u16* pO   = (u16*)(ws + 7*SZ_SD + 4*SZ_W);           // 32 MiB: [4][16][16][4096][4] u16
  float2* pml = (float2*)(ws + 11*SZ_SD + 4*SZ_W);     // 2 MiB: [4][16][4096] float2

  const float QSCALE = 0.18033688011112042f;   // 0.125 * log2(e)

  cvt3_kernel<<<dim3(4096,3),256,0,stream>>>(Q, Km, V, Qb, Kb, Vb);
  tcvt_qkv_kernel<<<dim3(16,3,16),256,0,stream>>>(WQ, WK, WV, WtQ, WtK, WtV);
  tcvt_wo_kernel<<<dim3(16,16),256,0,stream>>>(WO, WtO);
  gemm_qkv_kernel<<<dim3(8,32,3),512,0,stream>>>(Qb, Kb, Vb, WtQ, WtK, WtV,
                                                 bQ, bK, bV, qbuf, kbuf, vtb, QSCALE);
  flash_attn_kernel<<<dim3(1024),512,0,stream>>>(qbuf, kbuf, vtb, pO, pml);
  combine_kernel<<<dim3(256,16),256,0,stream>>>(pO, pml, catb);
  gemm_out_kernel<<<dim3(8,32),512,0,stream>>>(catb, WtO, bO, out, S_LEN, D_MODEL, D_MODEL);
}